// Round 4
// baseline (193.413 us; speedup 1.0000x reference)
//
#include <hip/hip_runtime.h>
#include <hip/hip_bf16.h>

// ---------------------------------------------------------------------------
// GNNBase: B=512, N=32, F=16, H=128, E=16, NE=3, L=2, D0=32
//   k_prep : xj table + pre-padded bf16 W^T images; LN affine folded into
//            next-layer weights (rows sigma-permuted) + folded biases in g_bf
//   k_mask : classify pairs (big: cnt>16 / small) via block-aggregated
//            compaction (2 atomics per block)
//   k_pair : PERSISTENT: 256 blocks x 512 thr (1/CU), ALL weights staged to
//            LDS once; each wave loops over tasks with ZERO inner barriers
//            (per-wave private X tile). Task = big pair (compacted rows) or
//            two packed small pairs. LN normalize-only in C-frag regs.
//   k_score/k_stats/k_final unchanged
//
// sigma column permutation: position p <-> orig channel
//   ch(p) = 32*(p>>5) + 16*(p&1) + ((p>>1)&15)
// ---------------------------------------------------------------------------

typedef __attribute__((ext_vector_type(8))) __bf16 bf16x8;
typedef __attribute__((ext_vector_type(4))) float  f32x4;
typedef __attribute__((ext_vector_type(2))) float  f32x2;

__device__ float g_bf[256];   // folded biases: [0:128)=layer1, [128:256)=layer2

__device__ __forceinline__ unsigned short f2bf(float f) {
  union { float f; unsigned u; } v; v.f = f;
  unsigned u = v.u;
  u += 0x7FFFu + ((u >> 16) & 1u);   // RTNE
  return (unsigned short)(u >> 16);
}

__device__ __forceinline__ unsigned pk2bf(float a, float b) {
  union { __hip_bfloat162 h; unsigned u; } cv;
  cv.h = __float22bfloat162_rn(make_float2(a, b));   // .x -> low 16
  return cv.u;
}

__device__ __forceinline__ bf16x8 lds_frag(const unsigned short* p) {
  union { uint4 u; bf16x8 v; } x;
  x.u = *(const uint4*)p;            // ds_read_b128
  return x.v;
}

__device__ __forceinline__ f32x4 mfma16(bf16x8 a, bf16x8 b, f32x4 c) {
  return __builtin_amdgcn_mfma_f32_16x16x32_bf16(a, b, c, 0, 0, 0);
}

// 16-lane butterfly sum via DPP (returns full sum in all lanes of each row16)
__device__ __forceinline__ float dpp_add16(float x) {
  union { float f; int i; } a, t;
  a.f = x;
  t.i = __builtin_amdgcn_update_dpp(0, a.i, 0xB1,  0xF, 0xF, true); a.f += t.f; // quad_perm xor1
  t.i = __builtin_amdgcn_update_dpp(0, a.i, 0x4E,  0xF, 0xF, true); a.f += t.f; // quad_perm xor2
  t.i = __builtin_amdgcn_update_dpp(0, a.i, 0x141, 0xF, 0xF, true); a.f += t.f; // row_half_mirror
  t.i = __builtin_amdgcn_update_dpp(0, a.i, 0x140, 0xF, 0xF, true); a.f += t.f; // row_mirror
  return a.f;
}

// async global->LDS, 16 B per lane. LDS dest = wave-uniform base + lane*16.
__device__ __forceinline__ void gll16(const void* g, void* l) {
  __builtin_amdgcn_global_load_lds(
      (const __attribute__((address_space(1))) unsigned int*)(unsigned long long)g,
      (__attribute__((address_space(3))) unsigned int*)(unsigned int)(unsigned long long)l,
      16, 0, 0);
}

// ---------------------------------------------------------------------------
// workspace layout (bytes)
// ---------------------------------------------------------------------------
#define WS_HB    0           // bf16 h [16384][128] (sigma order)   4194304
#define WS_HSEL  4194304     // f32  h agent rows [512][128] (orig)  262144
#define WS_SWS   4456448     // f32 scores [16384] / task lists       65536
#define WS_STATS 4521984     // f32 [2] stats; +16: task counters       256
#define WS_XJB   4522240     // bf16 xj [16384][32]                 1048576
#define WS_WT0P  5570816     // bf16 lin1 W^T [128][40]               10240
#define WS_W1P   5581056     // bf16 folded linh0 W^T [2][128][72]    36864
#define WS_W2P   5617920     // bf16 folded linh1 W^T [2][128][72]    36864
#define WS_WT3P  5654784     // bf16 fc2a W^T [128][136] (sigma rows) 34816

// ---------------------------------------------------------------------------
// k_prep
// ---------------------------------------------------------------------------
#define PREP_N0 524288                 // xjb elements
#define PREP_N1 (PREP_N0 + 5120)      // + WT0p [128][40]
#define PREP_N2 (PREP_N1 + 36864)     // + W1p/W2p [2l][2h][128][72]
#define PREP_N3 (PREP_N2 + 17408)     // + WT3p [128][136]
#define PREP_N4 (PREP_N3 + 256)      // + folded biases
#define PREP_N5 (PREP_N4 + 2)        // + zero task counters

__global__ void k_prep(const float* __restrict__ node_obs, const float* __restrict__ ent_emb,
                       const float* __restrict__ lin1_w, const float* __restrict__ linh_w,
                       const float* __restrict__ fc2a_w,
                       const float* __restrict__ ln1_g, const float* __restrict__ ln1_b,
                       const float* __restrict__ lnh_g, const float* __restrict__ lnh_b,
                       const float* __restrict__ linh_b,
                       char* __restrict__ ws) {
  int idx = blockIdx.x * 256 + threadIdx.x;
  unsigned short* xjb  = (unsigned short*)(ws + WS_XJB);
  unsigned short* WT0p = (unsigned short*)(ws + WS_WT0P);
  unsigned short* W1p  = (unsigned short*)(ws + WS_W1P);
  unsigned short* W2p  = (unsigned short*)(ws + WS_W2P);
  unsigned short* WT3p = (unsigned short*)(ws + WS_WT3P);
  if (idx < PREP_N0) {
    int row = idx >> 5, k = idx & 31;
    float val;
    if (k < 15) val = node_obs[row * 16 + k];
    else if (k < 31) {
      int ent = (int)node_obs[row * 16 + 15];
      val = ent_emb[ent * 16 + (k - 15)];
    } else val = 0.f;   // e slot, patched per-wave in k_pair
    xjb[idx] = f2bf(val);
  } else if (idx < PREP_N1) {
    int r = idx - PREP_N0;
    int n = r / 40, kk = r - n * 40;
    WT0p[n * 40 + kk] = (kk < 32) ? f2bf(lin1_w[kk * 128 + n]) : (unsigned short)0;
  } else if (idx < PREP_N2) {
    int r = idx - PREP_N1;
    int l = r / 18432; r -= l * 18432;
    int h = r / 9216;  r -= h * 9216;
    int n = r / 72;    int kk = r - n * 72;
    unsigned short v = 0;
    if (kk < 64) {
      int p  = h * 64 + kk;                                    // sigma position
      int ok = 32 * (p >> 5) + 16 * (p & 1) + ((p >> 1) & 15); // orig channel
      float g = l ? lnh_g[ok] : ln1_g[ok];                     // fold prev LN gain
      v = f2bf(g * linh_w[l * 16384 + ok * 128 + n]);
    }
    (l ? W2p : W1p)[h * 9216 + n * 72 + kk] = v;
  } else if (idx < PREP_N3) {
    int r = idx - PREP_N2;
    int n = r / 136, kk = r - n * 136;
    unsigned short v = 0;
    if (kk < 128) {
      int ok = 32 * (kk >> 5) + 16 * (kk & 1) + ((kk >> 1) & 15);
      v = f2bf(fc2a_w[ok * 128 + n]);
    }
    WT3p[n * 136 + kk] = v;
  } else if (idx < PREP_N4) {
    // folded biases: b'[n] = linh_b[l][n] + beta_prev @ W[l][:,n]
    int r = idx - PREP_N3;
    int which = r >> 7, n = r & 127;
    const float* be = which ? lnh_b : ln1_b;   // beta of the preceding LN
    const float* w  = linh_w + which * 16384 + n;
    float a = linh_b[which * 128 + n];
#pragma unroll 8
    for (int k = 0; k < 128; ++k) a += be[k] * w[k * 128];
    g_bf[which * 128 + n] = a;
  } else if (idx < PREP_N5) {
    ((unsigned*)(ws + WS_STATS + 16))[idx - PREP_N4] = 0u;  // task counters
  }
}

// ---------------------------------------------------------------------------
// k_mask: classify all 16384 (b,c) pairs. cnt>16 -> big list, else small list.
// Block-aggregated compaction: ballot -> wave counts -> 1 scan -> 2 atomics
// per BLOCK. Lists overlay the scores region (free until k_score).
// ---------------------------------------------------------------------------
__global__ __launch_bounds__(256)
void k_mask(const float* __restrict__ adj, char* __restrict__ ws) {
  const int tid = threadIdx.x, lane = tid & 63, wv = tid >> 6;
  int p = blockIdx.x * 256 + tid;   // pair id; consecutive p -> consecutive c (coalesced)
  int b = p >> 5, c = p & 31;
  int cnt = 0;
#pragma unroll 8
  for (int r = 0; r < 32; ++r) {
    float a = adj[(b * 32 + r) * 32 + c];
    cnt += (a > 0.f && a < 1.f) ? 1 : 0;
  }
  const bool big = cnt > 16;
  unsigned long long bal = __ballot(big);
  __shared__ unsigned sb[4], ss[4];
  __shared__ unsigned base_b, base_s;
  if (lane == 0) {
    unsigned nb = (unsigned)__popcll(bal);
    sb[wv] = nb; ss[wv] = 64u - nb;
  }
  __syncthreads();
  if (tid == 0) {
    unsigned tb = 0, ts = 0;
#pragma unroll
    for (int i = 0; i < 4; ++i) {
      unsigned t = sb[i]; sb[i] = tb; tb += t;
      t = ss[i]; ss[i] = ts; ts += t;
    }
    unsigned* tcnt = (unsigned*)(ws + WS_STATS + 16);
    base_b = atomicAdd(&tcnt[0], tb);
    base_s = atomicAdd(&tcnt[1], ts);
  }
  __syncthreads();
  unsigned long long mlow = (1ull << lane) - 1ull;
  unsigned short* bigl = (unsigned short*)(ws + WS_SWS);
  unsigned short* smal = bigl + 16384;
  if (big) {
    unsigned rk = base_b + sb[wv] + (unsigned)__popcll(bal & mlow);
    bigl[rk] = (unsigned short)p;
  } else {
    unsigned rk = base_s + ss[wv] + (unsigned)__popcll(~bal & mlow);
    smal[rk] = (unsigned short)p;
  }
}

// ---------------------------------------------------------------------------
// epilogues. C-frag (16x16x32): col = tj*16+(lane&15), row = ti*16+quad*4+reg.
// Bias pre-loaded into accumulator; LN affine folded downstream.
// ---------------------------------------------------------------------------
__device__ __forceinline__ void bias_acc(f32x4 (&acc)[2][8], const float (&b8)[8]) {
#pragma unroll
  for (int tj = 0; tj < 8; ++tj)
#pragma unroll
    for (int ti = 0; ti < 2; ++ti)
#pragma unroll
      for (int q = 0; q < 4; ++q) acc[ti][tj][q] = b8[tj];
}

// normalize-only LN, sigma-packed b32 stores into the wave's private tile.
__device__ __forceinline__ void epilogue_store(f32x4 (&acc)[2][8],
    unsigned short* Xw, int li, int quad) {
  const f32x2 z2 = {0.f, 0.f};
#pragma unroll
  for (int ti = 0; ti < 2; ++ti) {
#pragma unroll
    for (int rp = 0; rp < 2; ++rp) {          // row pair (2*rp, 2*rp+1)
      f32x2 vv[8], s1 = {0.f, 0.f}, s2 = {0.f, 0.f};
#pragma unroll
      for (int tj = 0; tj < 8; ++tj) {
        f32x2 x = { acc[ti][tj][2 * rp], acc[ti][tj][2 * rp + 1] };
        x = __builtin_elementwise_max(x, z2);   // relu (v_pk_max_f32)
        vv[tj] = x; s1 += x; s2 += x * x;
      }
      f32x2 S1 = { dpp_add16(s1.x), dpp_add16(s1.y) };
      f32x2 S2 = { dpp_add16(s2.x), dpp_add16(s2.y) };
      f32x2 mean = S1 * 0.0078125f;
      f32x2 var  = S2 * 0.0078125f - mean * mean;
      f32x2 inv  = { rsqrtf(var.x + 1e-5f), rsqrtf(var.y + 1e-5f) };
      f32x2 c0   = -mean * inv;
      int r0 = ti * 16 + quad * 4 + 2 * rp;
      unsigned* d0 = (unsigned*)(Xw + r0 * 136);
      unsigned* d1 = (unsigned*)(Xw + (r0 + 1) * 136);
#pragma unroll
      for (int g4 = 0; g4 < 4; ++g4) {
        f32x2 oa = vv[2 * g4]     * inv + c0;   // sigma-even col
        f32x2 ob = vv[2 * g4 + 1] * inv + c0;   // sigma-odd col
        d0[g4 * 16 + li] = pk2bf(oa.x, ob.x);   // ds_write_b32, 2-way = free
        d1[g4 * 16 + li] = pk2bf(oa.y, ob.y);
      }
    }
  }
}

// quad-reduce T/Q and write one h row (sigma-order bf16) + optional hsel (f32).
__device__ __forceinline__ void agg_reduce_write(float (&T)[8], float Q, float NM,
    const float (&gg8)[8], const float (&be8)[8],
    int pair, const int* __restrict__ agent_id, char* __restrict__ ws,
    int li, int quad) {
#pragma unroll
  for (int tj = 0; tj < 8; ++tj) {
    T[tj] += __shfl_xor(T[tj], 16);
    T[tj] += __shfl_xor(T[tj], 32);
  }
  Q += __shfl_xor(Q, 16); Q += __shfl_xor(Q, 32);
  if (quad != 0 || pair < 0) return;
  float cs[8];
#pragma unroll
  for (int tj = 0; tj < 8; ++tj)
    cs[tj] = gg8[tj] * (T[tj] - Q) + NM * be8[tj];
  unsigned* hb32 = (unsigned*)((unsigned short*)(ws + WS_HB) + pair * 128);
#pragma unroll
  for (int g4 = 0; g4 < 4; ++g4)
    hb32[g4 * 16 + li] = pk2bf(cs[2 * g4], cs[2 * g4 + 1]);
  int b = pair >> 5;
  if ((pair & 31) == agent_id[b]) {
    float* hs = (float*)(ws + WS_HSEL) + b * 128;
#pragma unroll
    for (int tj = 0; tj < 8; ++tj) hs[tj * 16 + li] = cs[tj];  // orig order
  }
}

// final layer: normalize then masked sum over compacted live rows (row < cnt).
__device__ __forceinline__ void epilogue_agg2(f32x4 (&acc)[2][8],
    const float (&gg8)[8], const float (&be8)[8],
    int big, int cnt0, int cnt1, int p0, int p1,
    const int* __restrict__ agent_id, char* __restrict__ ws,
    int li, int quad) {
  const f32x2 z2 = {0.f, 0.f};
  float T0[8], T1[8], Q0 = 0.f, Q1 = 0.f;
#pragma unroll
  for (int ti = 0; ti < 2; ++ti) {
    f32x2 Tp[8];
#pragma unroll
    for (int tj = 0; tj < 8; ++tj) Tp[tj] = z2;
    f32x2 Qp = z2;
    float lim   = big ? (float)(cnt0 + cnt1) : (float)(ti ? cnt1 : cnt0);
    float rbase = (float)((big ? ti * 16 : 0) + quad * 4);
#pragma unroll
    for (int rp = 0; rp < 2; ++rp) {
      f32x2 vv[8], s1 = z2, s2 = z2;
#pragma unroll
      for (int tj = 0; tj < 8; ++tj) {
        f32x2 x = { acc[ti][tj][2 * rp], acc[ti][tj][2 * rp + 1] };
        x = __builtin_elementwise_max(x, z2);
        vv[tj] = x; s1 += x; s2 += x * x;
      }
      f32x2 S1 = { dpp_add16(s1.x), dpp_add16(s1.y) };
      f32x2 S2 = { dpp_add16(s2.x), dpp_add16(s2.y) };
      f32x2 mean = S1 * 0.0078125f;
      f32x2 var  = S2 * 0.0078125f - mean * mean;
      f32x2 inv  = { rsqrtf(var.x + 1e-5f), rsqrtf(var.y + 1e-5f) };
      float r0f = rbase + (float)(2 * rp);
      f32x2 mk = { (r0f < lim) ? 1.f : 0.f, (r0f + 1.f < lim) ? 1.f : 0.f };
      f32x2 u = mk * inv;
      Qp += u * mean;
#pragma unroll
      for (int tj = 0; tj < 8; ++tj) Tp[tj] += u * vv[tj];
    }
    if (ti == 0) {
#pragma unroll
      for (int tj = 0; tj < 8; ++tj) T0[tj] = Tp[tj].x + Tp[tj].y;
      Q0 = Qp.x + Qp.y;
    } else {
#pragma unroll
      for (int tj = 0; tj < 8; ++tj) T1[tj] = Tp[tj].x + Tp[tj].y;
      Q1 = Qp.x + Qp.y;
    }
  }
  if (big) {
#pragma unroll
    for (int tj = 0; tj < 8; ++tj) T0[tj] += T1[tj];
    Q0 += Q1;
    agg_reduce_write(T0, Q0, (float)(cnt0 + cnt1), gg8, be8, p0, agent_id, ws, li, quad);
  } else {
    agg_reduce_write(T0, Q0, (float)cnt0, gg8, be8, p0, agent_id, ws, li, quad);
    agg_reduce_write(T1, Q1, (float)cnt1, gg8, be8, p1, agent_id, ws, li, quad);
  }
}

// ---------------------------------------------------------------------------
// k_pair (persistent). LDS: resident weights [W0 10240][W1 36864][W2 36864]
// + 8 per-wave X tiles (32x136 bf16 = 8704 B; first 2560 B double as the
// 32x40 xj tile) + 8x128 B compaction scratch = 154624 B -> 1 block/CU.
// No barriers after the weight prologue: each wave owns its tile.
// ---------------------------------------------------------------------------
#define PL_W0    0
#define PL_W1    10240
#define PL_W2    47104
#define PL_XS    83968
#define PL_SCR   153600
#define PL_TOTAL 154624

__device__ __forceinline__ void mfma_fullK(f32x4 (&acc)[2][8],
    const unsigned short* Xw, const unsigned short* Wl, int li, int quad) {
#pragma unroll
  for (int s = 0; s < 4; ++s) {
    const unsigned short* Wh = Wl + (s >> 1) * 9216;   // half-K images
    const int ko = (s & 1) * 32 + quad * 8;
    bf16x8 a0 = lds_frag(Xw + li * 136 + s * 32 + quad * 8);
    bf16x8 a1 = lds_frag(Xw + (16 + li) * 136 + s * 32 + quad * 8);
#pragma unroll
    for (int tj = 0; tj < 8; ++tj) {
      bf16x8 bb = lds_frag(Wh + (tj * 16 + li) * 72 + ko);
      acc[0][tj] = mfma16(a0, bb, acc[0][tj]);
      acc[1][tj] = mfma16(a1, bb, acc[1][tj]);
    }
  }
}

__global__ __launch_bounds__(512, 2)
void k_pair(const float* __restrict__ adj, const int* __restrict__ agent_id,
            const float* __restrict__ lin1_b,
            const float* __restrict__ lnh_g, const float* __restrict__ lnh_b,
            char* __restrict__ ws) {
  __shared__ alignas(16) char smem[PL_TOTAL];
  const int tid  = threadIdx.x;
  const int lane = tid & 63, li = lane & 15, quad = lane >> 4, wv = tid >> 6;

  // ---- prologue: stage ALL weights (83968 B contiguous from WS_WT0P) ----
  {
    const char* g = ws + WS_WT0P;
    int off = tid * 16;
#pragma unroll
    for (int i = 0; i < 10; ++i) gll16(g + off + i * 8192, smem + off + i * 8192);
    if (tid < 128) gll16(g + off + 81920, smem + off + 81920);
  }

  const unsigned* tcnt = (const unsigned*)(ws + WS_STATS + 16);
  const int n_big = (int)tcnt[0], n_small = (int)tcnt[1];
  const int n_task = n_big + ((n_small + 1) >> 1);
  const unsigned short* bigl = (const unsigned short*)(ws + WS_SWS);
  const unsigned short* smal = bigl + 16384;
  const unsigned short* xjb  = (const unsigned short*)(ws + WS_XJB);

  unsigned short* Xw = (unsigned short*)(smem + PL_XS + wv * 8704);
  unsigned*      scr = (unsigned*)(smem + PL_SCR + wv * 128);
  const unsigned short* W0 = (const unsigned short*)(smem + PL_W0);
  const unsigned short* W1 = (const unsigned short*)(smem + PL_W1);
  const unsigned short* W2 = (const unsigned short*)(smem + PL_W2);

  // loop-invariant params -> registers
  float b0_[8], b1_[8], b2_[8], gg8[8], be8[8];
#pragma unroll
  for (int tj = 0; tj < 8; ++tj) {
    int col = tj * 16 + li;
    b0_[tj] = lin1_b[col];
    b1_[tj] = g_bf[col];
    b2_[tj] = g_bf[128 + col];
    gg8[tj] = lnh_g[128 + col];
    be8[tj] = lnh_b[128 + col];
  }

  __syncthreads();   // weights resident (vmcnt drained by barrier)

  const int r = lane & 31, hh = lane >> 5;

  for (int slot = (int)blockIdx.x * 8 + wv; slot < n_task; slot += 2048) {
    // ---- task decode ----
    int p0, p1 = -1, big = 0;
    if (slot < n_big) { p0 = bigl[slot]; big = 1; }
    else {
      int j = slot - n_big;
      p0 = smal[2 * j];
      p1 = (2 * j + 1 < n_small) ? smal[2 * j + 1] : -1;
    }

    // ---- mask + row compaction ----
    int pp = big ? (hh ? -1 : p0) : (hh ? p1 : p0);
    float a_val = 0.f;
    if (pp >= 0) a_val = adj[(((pp >> 5) * 32 + r) * 32) + (pp & 31)];
    const bool live = (a_val > 0.f) && (a_val < 1.f);
    unsigned long long bal = __ballot(live);
    unsigned hm = hh ? (unsigned)(bal >> 32) : (unsigned)bal;
    int pre = __popc(hm & ((1u << r) - 1u));
    int slot_in = big ? pre : (hh * 16 + pre);
    int cnt0, cnt1;
    if (big) { int ca = __popc((unsigned)bal); cnt0 = ca < 16 ? ca : 16; cnt1 = ca - cnt0; }
    else     { cnt0 = __popc((unsigned)bal); cnt1 = __popc((unsigned)(bal >> 32)); }
    if (live) scr[slot_in] = (unsigned)r;

    // ---- compacted xj gather into the wave tile (stride 40) ----
    {
      const uint4* src = (const uint4*)xjb;
      char* tile = (char*)Xw;
      int j0 = lane >> 2, j1 = 16 + (lane >> 2), pt = lane & 3;
      int ca = cnt0 + cnt1;
      bool v0 = j0 < (big ? ca : cnt0);
      bool v1 = big ? (j1 < ca) : ((j1 - 16) < cnt1);
      int b0 = (p0 < 0 ? 0 : p0 >> 5);
      int b1 = (p1 < 0 ? 0 : p1 >> 5);
      int sb1 = big ? b0 : b1;
      unsigned sr0 = v0 ? scr[j0] : 0u;
      unsigned sr1 = v1 ? scr[j1] : 0u;
      uint4 z4 = {0u, 0u, 0u, 0u};
      uint4 q0 = v0 ? src[(b0 * 32 + (int)sr0) * 4 + pt] : z4;
      uint4 q1 = v1 ? src[(sb1 * 32 + (int)sr1) * 4 + pt] : z4;
      *(uint4*)(tile + j0 * 80 + pt * 16) = q0;
      *(uint4*)(tile + j1 * 80 + pt * 16) = q1;
      if (live) ((unsigned short*)(tile + slot_in * 80))[31] = f2bf(a_val);
    }

    f32x4 acc[2][8];

    // ---- layer 0: [32 rows] x [K=32] @ lin1 ----
    bias_acc(acc, b0_);
    {
      const unsigned short* xt = Xw;
      bf16x8 a0 = lds_frag(xt + li * 40 + quad * 8);
      bf16x8 a1 = lds_frag(xt + (li + 16) * 40 + quad * 8);
#pragma unroll
      for (int tj = 0; tj < 8; ++tj) {
        bf16x8 bb = lds_frag(W0 + (tj * 16 + li) * 40 + quad * 8);
        acc[0][tj] = mfma16(a0, bb, acc[0][tj]);
        acc[1][tj] = mfma16(a1, bb, acc[1][tj]);
      }
    }
    epilogue_store(acc, Xw, li, quad);

    // ---- hidden layer 1 ----
    bias_acc(acc, b1_);
    mfma_fullK(acc, Xw, W1, li, quad);
    epilogue_store(acc, Xw, li, quad);

    // ---- hidden layer 2 + masked aggregate ----
    bias_acc(acc, b2_);
    mfma_fullK(acc, Xw, W2, li, quad);
    epilogue_agg2(acc, gg8, be8, big, cnt0, cnt1, p0, p1, agent_id, ws, li, quad);
  }
}

// ---------------------------------------------------------------------------
// k_score: s[row] = relu(h@fc2a+b)@fc2b + b2, 128 rows/block via MFMA.
// (h and fc2a^T are both sigma-ordered -> dot product invariant)
// ---------------------------------------------------------------------------
#define SC_TOTAL 70656
__global__ __launch_bounds__(256, 2)
void k_score(const char* __restrict__ ws,
             const float* __restrict__ fc2a_b, const float* __restrict__ fc2b_w,
             const float* __restrict__ fc2b_b) {
  __shared__ alignas(16) char smem[SC_TOTAL];
  unsigned short* Xs = (unsigned short*)smem;
  unsigned short* Ws = (unsigned short*)(smem + 34816);
  float* P = (float*)(smem + 69632);
  const int tid = threadIdx.x;
  const int row0 = blockIdx.x * 128;
  const uint4* hb4 = (const uint4*)(ws + WS_HB);
  const char* WT3p = ws + WS_WT3P;
  float* sws = (float*)((char*)ws + WS_SWS);

  for (int i = tid; i < 2048; i += 256) {      // hb rows -> padded Xs
    int row = i >> 4, ch = i & 15;
    uint4 v = hb4[(row0 + row) * 16 + ch];
    *(uint4*)(Xs + row * 136 + ch * 8) = v;
  }
  {                                            // WT3p image: 34816 B
    int off = tid * 16;
#pragma unroll
    for (int it = 0; it < 8; ++it) gll16(WT3p + off + it * 4096, smem + 34816 + off + it * 4096);
    if (tid < 128) gll16(WT3p + off + 32768, smem + 34816 + off + 32768);
  }
  if (tid < 128) { P[tid] = fc2a_b[tid]; P[128 + tid] = fc2b_w[tid]; }
  __syncthreads();

  const int lane = tid & 63, li = lane & 15, quad = lane >> 4, wv = tid >> 6;
  f32x4 acc[2][8];
#pragma unroll
  for (int ti = 0; ti < 2; ++ti)
#pragma unroll
    for (int tj = 0; tj < 8; ++tj)
#pragma unroll
      for (int q = 0; q < 4; ++q) acc[ti][tj][q] = 0.f;
#pragma unroll
  for (int s = 0; s < 4; ++s) {
    bf16x8 a0 = lds_frag(Xs + (32 * wv + li) * 136 + s * 32 + quad * 8);
    bf16x8 a1 = lds_frag(Xs + (32 * wv + 16 + li) * 136 + s * 32 + quad * 8);
#pragma unroll
    for (int tj = 0; tj < 8; ++tj) {
      bf16x8 bb = lds_frag(Ws + (tj * 16 + li) * 136 + s * 32 + quad * 8);
      acc[0][tj] = mfma16(a0, bb, acc[0][tj]);
      acc[1][tj] = mfma16(a1, bb, acc[1][tj]);
    }
  }
  float bs[8], w2[8];
#pragma unroll
  for (int tj = 0; tj < 8; ++tj) {
    bs[tj] = P[tj * 16 + li];
    w2[tj] = P[128 + tj * 16 + li];
  }
  float b2 = fc2b_b[0];
#pragma unroll
  for (int ti = 0; ti < 2; ++ti) {
#pragma unroll
    for (int rg = 0; rg < 4; ++rg) {
      float t = 0.f;
#pragma unroll
      for (int tj = 0; tj < 8; ++tj) {
        float x = acc[ti][tj][rg] + bs[tj];
        x = fmaxf(x, 0.f);
        t += x * w2[tj];
      }
#pragma unroll
      for (int m = 1; m < 16; m <<= 1) t += __shfl_xor(t, m);
      if (li == 0) sws[row0 + 32 * wv + ti * 16 + quad * 4 + rg] = t + b2;
    }
  }
}

// ---------------------------------------------------------------------------
// k_stats: softmax max & sum over 16384 scores (single block).
// ---------------------------------------------------------------------------
__global__ __launch_bounds__(1024)
void k_stats(char* __restrict__ ws) {
  const float* sws = (const float*)(ws + WS_SWS);
  float* stats = (float*)(ws + WS_STATS);
  __shared__ float red[1024];
  const int tid = threadIdx.x;
  float m = -3.0e38f;
  for (int i = tid; i < 16384; i += 1024) m = fmaxf(m, sws[i]);
  red[tid] = m;
  __syncthreads();
  for (int st = 512; st > 0; st >>= 1) {
    if (tid < st) red[tid] = fmaxf(red[tid], red[tid + st]);
    __syncthreads();
  }
  float mx = red[0];
  __syncthreads();
  float sm = 0.f;
  for (int i = tid; i < 16384; i += 1024) sm += __expf(sws[i] - mx);
  red[tid] = sm;
  __syncthreads();
  for (int st = 512; st > 0; st >>= 1) {
    if (tid < st) red[tid] += red[tid + st];
    __syncthreads();
  }
  if (tid == 0) { stats[0] = mx; stats[1] = red[0]; }
}

// ---------------------------------------------------------------------------
// k_final: 512 agent rows only.
// ---------------------------------------------------------------------------
__global__ __launch_bounds__(128)
void k_final(const char* __restrict__ ws, const int* __restrict__ agent_id,
             const float* __restrict__ fc3_w, const float* __restrict__ fc3_b,
             const float* __restrict__ ln3_g, const float* __restrict__ ln3_b,
             const float* __restrict__ fc4_w, const float* __restrict__ fc4_b,
             const float* __restrict__ ln4_g, const float* __restrict__ ln4_b,
             float* __restrict__ out) {
  const float* hsel  = (const float*)(ws + WS_HSEL);
  const float* sws   = (const float*)(ws + WS_SWS);
  const float* stats = (const float*)(ws + WS_STATS);
  __shared__ float xrow[128];
  __shared__ float red[8];
  const int tid = threadIdx.x;
  const int b = blockIdx.x;
  xrow[tid] = hsel[b * 128 + tid];
  __syncthreads();
  float t = fc3_b[tid];
  for (int k = 0; k < 128; ++k) t += xrow[k] * fc3_w[k * 128 + tid];
  t = fmaxf(t, 0.f);
  float s1 = t, s2 = t * t;
#pragma unroll
  for (int m = 1; m < 64; m <<= 1) { s1 += __shfl_xor(s1, m); s2 += __shfl_xor(s2, m); }
  if ((tid & 63) == 0) { red[(tid >> 6) * 2] = s1; red[(tid >> 6) * 2 + 1] = s2; }
  __syncthreads();
  s1 = red[0] + red[2]; s2 = red[1] + red[3];
  float mean = s1 * 0.0078125f;
  float var  = s2 * 0.0078125f - mean * mean;
  float inv  = rsqrtf(var + 1e-5f);
  float v = (t - mean) * inv * ln3_g[tid] + ln3_b[tid];
  float alpha = __expf(sws[b * 32 + agent_id[b]] - stats[0]) / stats[1];
  __syncthreads();
  xrow[tid] = alpha * v;
  __syncthreads();
  float x = fc4_b[tid];
  for (int k = 0; k < 128; ++k) x += xrow[k] * fc4_w[k * 128 + tid];
  x = fmaxf(x, 0.f);
  s1 = x; s2 = x * x;
#pragma unroll
  for (int m = 1; m < 64; m <<= 1) { s1 += __shfl_xor(s1, m); s2 += __shfl_xor(s2, m); }
  if ((tid & 63) == 0) { red[4 + (tid >> 6) * 2] = s1; red[5 + (tid >> 6) * 2] = s2; }
  __syncthreads();
  s1 = red[4] + red[6]; s2 = red[5] + red[7];
  mean = s1 * 0.0078125f;
  var  = s2 * 0.0078125f - mean * mean;
  inv  = rsqrtf(var + 1e-5f);
  out[b * 128 + tid] = (x - mean) * inv * ln4_g[tid] + ln4_b[tid];
}

// ---------------------------------------------------------------------------
extern "C" void kernel_launch(void* const* d_in, const int* in_sizes, int n_in,
                              void* d_out, int out_size, void* d_ws, size_t ws_size,
                              hipStream_t stream) {
  (void)in_sizes; (void)n_in; (void)out_size; (void)ws_size;
  const float* node_obs = (const float*)d_in[0];
  const float* adj      = (const float*)d_in[1];
  const int*   agent_id = (const int*)d_in[2];
  const float* ent_emb  = (const float*)d_in[3];
  const float* lin1_w   = (const float*)d_in[4];
  const float* lin1_b   = (const float*)d_in[5];
  const float* ln1_g    = (const float*)d_in[6];
  const float* ln1_beta = (const float*)d_in[7];
  const float* linh_w   = (const float*)d_in[8];
  const float* linh_b   = (const float*)d_in[9];
  const float* lnh_g    = (const float*)d_in[10];
  const float* lnh_b    = (const float*)d_in[11];
  // d_in[12] fc2a_w used in k_prep
  const float* fc2a_b   = (const float*)d_in[13];
  const float* fc2b_w   = (const float*)d_in[14];
  const float* fc2b_b   = (const float*)d_in[15];
  const float* fc3_w    = (const float*)d_in[16];
  const float* fc3_b    = (const float*)d_in[17];
  const float* ln3_g    = (const float*)d_in[18];
  const float* ln3_b    = (const float*)d_in[19];
  const float* fc4_w    = (const float*)d_in[20];
  const float* fc4_b    = (const float*)d_in[21];
  const float* ln4_g    = (const float*)d_in[22];
  const float* ln4_b    = (const float*)d_in[23];
  float* out = (float*)d_out;
  char* ws = (char*)d_ws;

  k_prep<<<(PREP_N5 + 255) / 256, 256, 0, stream>>>(node_obs, ent_emb, lin1_w, linh_w,
                                                    (const float*)d_in[12],
                                                    ln1_g, ln1_beta, lnh_g, lnh_b,
                                                    linh_b, ws);
  k_mask<<<64, 256, 0, stream>>>(adj, ws);
  k_pair<<<256, 512, 0, stream>>>(adj, agent_id, lin1_b, lnh_g, lnh_b, ws);
  k_score<<<128, 256, 0, stream>>>(ws, fc2a_b, fc2b_w, fc2b_b);
  k_stats<<<1, 1024, 0, stream>>>(ws);
  k_final<<<512, 128, 0, stream>>>(ws, agent_id,
                                   fc3_w, fc3_b, ln3_g, ln3_b,
                                   fc4_w, fc4_b, ln4_g, ln4_b, out);
}

// Round 7
// 183.050 us; speedup vs baseline: 1.0566x; 1.0566x over previous
//
#include <hip/hip_runtime.h>
#include <hip/hip_bf16.h>

// ---------------------------------------------------------------------------
// GNNBase: B=512, N=32, F=16, H=128, E=16, NE=3, L=2, D0=32
//   k_prep : xj table + pre-padded bf16 W^T images; LN affine folded into
//            next-layer weights (rows sigma-permuted) + folded biases in g_bf
//   k_mask : classify pairs (big: cnt>16 / small) via block-aggregated
//            compaction (2 atomics per block)                    [R3-proven]
//   k_pair : wave-task = 2 MFMA row-tiles: one big pair (rows compacted) or
//            TWO packed small pairs. LN normalize-only in C-frag regs.
//                                                                [R3-proven]
//   k_score: scores via MFMA + per-block softmax partials (max, expsum)
//            into device global g_ms   [NEW: k_stats fused away]
//   k_final: combines 128 partials -> (M, S), then 512 agent rows
//
// sigma column permutation: position p <-> orig channel
//   ch(p) = 32*(p>>5) + 16*(p&1) + ((p>>1)&15)
// ---------------------------------------------------------------------------

typedef __attribute__((ext_vector_type(8))) __bf16 bf16x8;
typedef __attribute__((ext_vector_type(4))) float  f32x4;
typedef __attribute__((ext_vector_type(2))) float  f32x2;

__device__ float g_bf[256];   // folded biases: [0:128)=layer1, [128:256)=layer2
__device__ float g_ms[256];   // softmax partials: [0:128)=max_b, [128:256)=sum_b

__device__ __forceinline__ unsigned short f2bf(float f) {
  union { float f; unsigned u; } v; v.f = f;
  unsigned u = v.u;
  u += 0x7FFFu + ((u >> 16) & 1u);   // RTNE
  return (unsigned short)(u >> 16);
}

__device__ __forceinline__ unsigned pk2bf(float a, float b) {
  union { __hip_bfloat162 h; unsigned u; } cv;
  cv.h = __float22bfloat162_rn(make_float2(a, b));   // .x -> low 16
  return cv.u;
}

__device__ __forceinline__ bf16x8 lds_frag(const unsigned short* p) {
  union { uint4 u; bf16x8 v; } x;
  x.u = *(const uint4*)p;            // ds_read_b128
  return x.v;
}

__device__ __forceinline__ f32x4 mfma16(bf16x8 a, bf16x8 b, f32x4 c) {
  return __builtin_amdgcn_mfma_f32_16x16x32_bf16(a, b, c, 0, 0, 0);
}

// 16-lane butterfly sum via DPP (returns full sum in all lanes of each row16)
__device__ __forceinline__ float dpp_add16(float x) {
  union { float f; int i; } a, t;
  a.f = x;
  t.i = __builtin_amdgcn_update_dpp(0, a.i, 0xB1,  0xF, 0xF, true); a.f += t.f; // quad_perm xor1
  t.i = __builtin_amdgcn_update_dpp(0, a.i, 0x4E,  0xF, 0xF, true); a.f += t.f; // quad_perm xor2
  t.i = __builtin_amdgcn_update_dpp(0, a.i, 0x141, 0xF, 0xF, true); a.f += t.f; // row_half_mirror
  t.i = __builtin_amdgcn_update_dpp(0, a.i, 0x140, 0xF, 0xF, true); a.f += t.f; // row_mirror
  return a.f;
}

// async global->LDS, 16 B per lane. LDS dest = wave-uniform base + lane*16.
__device__ __forceinline__ void gll16(const void* g, void* l) {
  __builtin_amdgcn_global_load_lds(
      (const __attribute__((address_space(1))) unsigned int*)(unsigned long long)g,
      (__attribute__((address_space(3))) unsigned int*)(unsigned int)(unsigned long long)l,
      16, 0, 0);
}

// copy a contiguous 18432-B pre-padded weight image into LDS (256 threads)
__device__ __forceinline__ void stage18432(const char* g, char* l, int tid) {
  int off = tid * 16;
  gll16(g + off,         l + off);
  gll16(g + off + 4096,  l + off + 4096);
  gll16(g + off + 8192,  l + off + 8192);
  gll16(g + off + 12288, l + off + 12288);
  if (tid < 128) gll16(g + off + 16384, l + off + 16384);
}

// ---------------------------------------------------------------------------
// workspace layout (bytes)
// ---------------------------------------------------------------------------
#define WS_HB    0           // bf16 h [16384][128] (sigma order)   4194304
#define WS_HSEL  4194304     // f32  h agent rows [512][128] (orig)  262144
#define WS_SWS   4456448     // f32 scores [16384] / task lists       65536
#define WS_STATS 4521984     // +16: task counters                      256
#define WS_XJB   4522240     // bf16 xj [16384][32]                 1048576
#define WS_WT0P  5570816     // bf16 lin1 W^T [128][40]               10240
#define WS_W1P   5581056     // bf16 folded linh0 W^T [2][128][72]    36864
#define WS_W2P   5617920     // bf16 folded linh1 W^T [2][128][72]    36864
#define WS_WT3P  5654784     // bf16 fc2a W^T [128][136] (sigma rows) 34816

// ---------------------------------------------------------------------------
// k_prep
// ---------------------------------------------------------------------------
#define PREP_N0 524288                 // xjb elements
#define PREP_N1 (PREP_N0 + 5120)      // + WT0p [128][40]
#define PREP_N2 (PREP_N1 + 36864)     // + W1p/W2p [2l][2h][128][72]
#define PREP_N3 (PREP_N2 + 17408)     // + WT3p [128][136]
#define PREP_N4 (PREP_N3 + 256)      // + folded biases
#define PREP_N5 (PREP_N4 + 2)        // + zero task counters

__global__ void k_prep(const float* __restrict__ node_obs, const float* __restrict__ ent_emb,
                       const float* __restrict__ lin1_w, const float* __restrict__ linh_w,
                       const float* __restrict__ fc2a_w,
                       const float* __restrict__ ln1_g, const float* __restrict__ ln1_b,
                       const float* __restrict__ lnh_g, const float* __restrict__ lnh_b,
                       const float* __restrict__ linh_b,
                       char* __restrict__ ws) {
  int idx = blockIdx.x * 256 + threadIdx.x;
  unsigned short* xjb  = (unsigned short*)(ws + WS_XJB);
  unsigned short* WT0p = (unsigned short*)(ws + WS_WT0P);
  unsigned short* W1p  = (unsigned short*)(ws + WS_W1P);
  unsigned short* W2p  = (unsigned short*)(ws + WS_W2P);
  unsigned short* WT3p = (unsigned short*)(ws + WS_WT3P);
  if (idx < PREP_N0) {
    int row = idx >> 5, k = idx & 31;
    float val;
    if (k < 15) val = node_obs[row * 16 + k];
    else if (k < 31) {
      int ent = (int)node_obs[row * 16 + 15];
      val = ent_emb[ent * 16 + (k - 15)];
    } else val = 0.f;   // e slot, patched per-wave in k_pair
    xjb[idx] = f2bf(val);
  } else if (idx < PREP_N1) {
    int r = idx - PREP_N0;
    int n = r / 40, kk = r - n * 40;
    WT0p[n * 40 + kk] = (kk < 32) ? f2bf(lin1_w[kk * 128 + n]) : (unsigned short)0;
  } else if (idx < PREP_N2) {
    int r = idx - PREP_N1;
    int l = r / 18432; r -= l * 18432;
    int h = r / 9216;  r -= h * 9216;
    int n = r / 72;    int kk = r - n * 72;
    unsigned short v = 0;
    if (kk < 64) {
      int p  = h * 64 + kk;                                    // sigma position
      int ok = 32 * (p >> 5) + 16 * (p & 1) + ((p >> 1) & 15); // orig channel
      float g = l ? lnh_g[ok] : ln1_g[ok];                     // fold prev LN gain
      v = f2bf(g * linh_w[l * 16384 + ok * 128 + n]);
    }
    (l ? W2p : W1p)[h * 9216 + n * 72 + kk] = v;
  } else if (idx < PREP_N3) {
    int r = idx - PREP_N2;
    int n = r / 136, kk = r - n * 136;
    unsigned short v = 0;
    if (kk < 128) {
      int ok = 32 * (kk >> 5) + 16 * (kk & 1) + ((kk >> 1) & 15);
      v = f2bf(fc2a_w[ok * 128 + n]);
    }
    WT3p[n * 136 + kk] = v;
  } else if (idx < PREP_N4) {
    // folded biases: b'[n] = linh_b[l][n] + beta_prev @ W[l][:,n]
    int r = idx - PREP_N3;
    int which = r >> 7, n = r & 127;
    const float* be = which ? lnh_b : ln1_b;   // beta of the preceding LN
    const float* w  = linh_w + which * 16384 + n;
    float a = linh_b[which * 128 + n];
#pragma unroll 8
    for (int k = 0; k < 128; ++k) a += be[k] * w[k * 128];
    g_bf[which * 128 + n] = a;
  } else if (idx < PREP_N5) {
    ((unsigned*)(ws + WS_STATS + 16))[idx - PREP_N4] = 0u;  // task counters
  }
}

// ---------------------------------------------------------------------------
// k_mask: classify all 16384 (b,c) pairs. cnt>16 -> big list, else small list.
// Block-aggregated compaction: ballot -> wave counts -> 1 scan -> 2 atomics
// per BLOCK. Lists overlay the scores region (free until k_score). [R3-proven]
// ---------------------------------------------------------------------------
__global__ __launch_bounds__(256)
void k_mask(const float* __restrict__ adj, char* __restrict__ ws) {
  const int tid = threadIdx.x, lane = tid & 63, wv = tid >> 6;
  int p = blockIdx.x * 256 + tid;   // pair id; consecutive p -> consecutive c (coalesced)
  int b = p >> 5, c = p & 31;
  int cnt = 0;
#pragma unroll 8
  for (int r = 0; r < 32; ++r) {
    float a = adj[(b * 32 + r) * 32 + c];
    cnt += (a > 0.f && a < 1.f) ? 1 : 0;
  }
  const bool big = cnt > 16;
  unsigned long long bal = __ballot(big);
  __shared__ unsigned sb[4], ss[4];
  __shared__ unsigned base_b, base_s;
  if (lane == 0) {
    unsigned nb = (unsigned)__popcll(bal);
    sb[wv] = nb; ss[wv] = 64u - nb;
  }
  __syncthreads();
  if (tid == 0) {
    unsigned tb = 0, ts = 0;
#pragma unroll
    for (int i = 0; i < 4; ++i) {
      unsigned t = sb[i]; sb[i] = tb; tb += t;
      t = ss[i]; ss[i] = ts; ts += t;
    }
    unsigned* tcnt = (unsigned*)(ws + WS_STATS + 16);
    base_b = atomicAdd(&tcnt[0], tb);
    base_s = atomicAdd(&tcnt[1], ts);
  }
  __syncthreads();
  unsigned long long mlow = (1ull << lane) - 1ull;
  unsigned short* bigl = (unsigned short*)(ws + WS_SWS);
  unsigned short* smal = bigl + 16384;
  if (big) {
    unsigned rk = base_b + sb[wv] + (unsigned)__popcll(bal & mlow);
    bigl[rk] = (unsigned short)p;
  } else {
    unsigned rk = base_s + ss[wv] + (unsigned)__popcll(~bal & mlow);
    smal[rk] = (unsigned short)p;
  }
}

// ---------------------------------------------------------------------------
// epilogues. C-frag (16x16x32): col = tj*16+(lane&15), row = ti*16+quad*4+reg.
// ---------------------------------------------------------------------------
__device__ __forceinline__ void bias_acc(f32x4 (&acc)[2][8],
                                         const float* __restrict__ gb, int li) {
#pragma unroll
  for (int tj = 0; tj < 8; ++tj) {
    float b = gb[tj * 16 + li];
#pragma unroll
    for (int ti = 0; ti < 2; ++ti)
#pragma unroll
      for (int q = 0; q < 4; ++q) acc[ti][tj][q] = b;
  }
}

__device__ __forceinline__ void epilogue_store(f32x4 (&acc)[2][8],
    unsigned short* Xs, int wv, int li, int quad) {
  const f32x2 z2 = {0.f, 0.f};
#pragma unroll
  for (int ti = 0; ti < 2; ++ti) {
#pragma unroll
    for (int rp = 0; rp < 2; ++rp) {          // row pair (2*rp, 2*rp+1)
      f32x2 vv[8], s1 = {0.f, 0.f}, s2 = {0.f, 0.f};
#pragma unroll
      for (int tj = 0; tj < 8; ++tj) {
        f32x2 x = { acc[ti][tj][2 * rp], acc[ti][tj][2 * rp + 1] };
        x = __builtin_elementwise_max(x, z2);   // relu (v_pk_max_f32)
        vv[tj] = x; s1 += x; s2 += x * x;
      }
      f32x2 S1 = { dpp_add16(s1.x), dpp_add16(s1.y) };
      f32x2 S2 = { dpp_add16(s2.x), dpp_add16(s2.y) };
      f32x2 mean = S1 * 0.0078125f;
      f32x2 var  = S2 * 0.0078125f - mean * mean;
      f32x2 inv  = { rsqrtf(var.x + 1e-5f), rsqrtf(var.y + 1e-5f) };
      f32x2 c0   = -mean * inv;
      int r0 = 32 * wv + ti * 16 + quad * 4 + 2 * rp;
      unsigned* d0 = (unsigned*)(Xs + r0 * 136);
      unsigned* d1 = (unsigned*)(Xs + (r0 + 1) * 136);
#pragma unroll
      for (int g4 = 0; g4 < 4; ++g4) {
        f32x2 oa = vv[2 * g4]     * inv + c0;   // sigma-even col
        f32x2 ob = vv[2 * g4 + 1] * inv + c0;   // sigma-odd col
        d0[g4 * 16 + li] = pk2bf(oa.x, ob.x);   // ds_write_b32, 2-way = free
        d1[g4 * 16 + li] = pk2bf(oa.y, ob.y);
      }
    }
  }
}

// quad-reduce T/Q and write one h row (sigma-order bf16) + optional hsel (f32).
__device__ __forceinline__ void agg_reduce_write(float (&T)[8], float Q, float NM,
    const float* __restrict__ gg, const float* __restrict__ gbe,
    int pair, const int* __restrict__ agent_id, char* __restrict__ ws,
    int li, int quad) {
#pragma unroll
  for (int tj = 0; tj < 8; ++tj) {
    T[tj] += __shfl_xor(T[tj], 16);
    T[tj] += __shfl_xor(T[tj], 32);
  }
  Q += __shfl_xor(Q, 16); Q += __shfl_xor(Q, 32);
  if (quad != 0 || pair < 0) return;
  float cs[8];
#pragma unroll
  for (int tj = 0; tj < 8; ++tj) {
    int col = tj * 16 + li;
    cs[tj] = gg[col] * (T[tj] - Q) + NM * gbe[col];
  }
  unsigned* hb32 = (unsigned*)((unsigned short*)(ws + WS_HB) + pair * 128);
#pragma unroll
  for (int g4 = 0; g4 < 4; ++g4)
    hb32[g4 * 16 + li] = pk2bf(cs[2 * g4], cs[2 * g4 + 1]);
  int b = pair >> 5;
  if ((pair & 31) == agent_id[b]) {
    float* hs = (float*)(ws + WS_HSEL) + b * 128;
#pragma unroll
    for (int tj = 0; tj < 8; ++tj) hs[tj * 16 + li] = cs[tj];  // orig order
  }
}

// final layer: normalize then masked sum. Compacted rows are live-contiguous:
// mask = (row < cnt), NM = cnt (scalar). Big pair: tiles sum to one dest;
// small pairs: one dest per tile.
__device__ __forceinline__ void epilogue_agg2(f32x4 (&acc)[2][8],
    const float* __restrict__ gg, const float* __restrict__ gbe,
    int big, int cnt0, int cnt1, int p0, int p1,
    const int* __restrict__ agent_id, char* __restrict__ ws,
    int li, int quad) {
  const f32x2 z2 = {0.f, 0.f};
  float T0[8], T1[8], Q0 = 0.f, Q1 = 0.f;
#pragma unroll
  for (int ti = 0; ti < 2; ++ti) {
    f32x2 Tp[8];
#pragma unroll
    for (int tj = 0; tj < 8; ++tj) Tp[tj] = z2;
    f32x2 Qp = z2;
    float lim   = big ? (float)(cnt0 + cnt1) : (float)(ti ? cnt1 : cnt0);
    float rbase = (float)((big ? ti * 16 : 0) + quad * 4);
#pragma unroll
    for (int rp = 0; rp < 2; ++rp) {
      f32x2 vv[8], s1 = z2, s2 = z2;
#pragma unroll
      for (int tj = 0; tj < 8; ++tj) {
        f32x2 x = { acc[ti][tj][2 * rp], acc[ti][tj][2 * rp + 1] };
        x = __builtin_elementwise_max(x, z2);
        vv[tj] = x; s1 += x; s2 += x * x;
      }
      f32x2 S1 = { dpp_add16(s1.x), dpp_add16(s1.y) };
      f32x2 S2 = { dpp_add16(s2.x), dpp_add16(s2.y) };
      f32x2 mean = S1 * 0.0078125f;
      f32x2 var  = S2 * 0.0078125f - mean * mean;
      f32x2 inv  = { rsqrtf(var.x + 1e-5f), rsqrtf(var.y + 1e-5f) };
      float r0f = rbase + (float)(2 * rp);
      f32x2 mk = { (r0f < lim) ? 1.f : 0.f, (r0f + 1.f < lim) ? 1.f : 0.f };
      f32x2 u = mk * inv;
      Qp += u * mean;
#pragma unroll
      for (int tj = 0; tj < 8; ++tj) Tp[tj] += u * vv[tj];
    }
    if (ti == 0) {
#pragma unroll
      for (int tj = 0; tj < 8; ++tj) T0[tj] = Tp[tj].x + Tp[tj].y;
      Q0 = Qp.x + Qp.y;
    } else {
#pragma unroll
      for (int tj = 0; tj < 8; ++tj) T1[tj] = Tp[tj].x + Tp[tj].y;
      Q1 = Qp.x + Qp.y;
    }
  }
  if (big) {
#pragma unroll
    for (int tj = 0; tj < 8; ++tj) T0[tj] += T1[tj];
    Q0 += Q1;
    agg_reduce_write(T0, Q0, (float)(cnt0 + cnt1), gg, gbe, p0, agent_id, ws, li, quad);
  } else {
    agg_reduce_write(T0, Q0, (float)cnt0, gg, gbe, p0, agent_id, ws, li, quad);
    agg_reduce_write(T1, Q1, (float)cnt1, gg, gbe, p1, agent_id, ws, li, quad);
  }
}

// ---------------------------------------------------------------------------
// k_pair. LDS: Xs [128][136] bf16 (first 10240 B overlaid by 4 per-wave
// 32x40 xj tiles during layer 0; +128 B/wave compaction scratch above) +
// Wh [128][72] bf16 half-K weight buffer. 53248 B -> 3 blocks/CU. [R3-proven]
// ---------------------------------------------------------------------------
#define SMP_W 34816
#define SMP_TOTAL 53248

__device__ __forceinline__ void mfma_half(f32x4 (&acc)[2][8],
    const unsigned short* Xs, const unsigned short* Wh,
    int xoff, int wv, int li, int quad) {
#pragma unroll
  for (int s = 0; s < 2; ++s) {
    bf16x8 a0 = lds_frag(Xs + (32 * wv + li) * 136 + xoff + s * 32 + quad * 8);
    bf16x8 a1 = lds_frag(Xs + (32 * wv + 16 + li) * 136 + xoff + s * 32 + quad * 8);
#pragma unroll
    for (int tj = 0; tj < 8; ++tj) {
      bf16x8 bb = lds_frag(Wh + (tj * 16 + li) * 72 + s * 32 + quad * 8);
      acc[0][tj] = mfma16(a0, bb, acc[0][tj]);
      acc[1][tj] = mfma16(a1, bb, acc[1][tj]);
    }
  }
}

__global__ __launch_bounds__(256, 3)
void k_pair(const float* __restrict__ adj, const int* __restrict__ agent_id,
            const float* __restrict__ lin1_b,
            const float* __restrict__ lnh_g, const float* __restrict__ lnh_b,
            char* __restrict__ ws) {
  __shared__ alignas(16) char smem[SMP_TOTAL];
  unsigned short* Xs = (unsigned short*)smem;
  unsigned short* Wh = (unsigned short*)(smem + SMP_W);

  const unsigned short* xjb = (const unsigned short*)(ws + WS_XJB);
  const char* WT0p = ws + WS_WT0P;
  const char* W1p  = ws + WS_W1P;
  const char* W2p  = ws + WS_W2P;

  const int tid  = threadIdx.x;
  const int lane = tid & 63, li = lane & 15, quad = lane >> 4, wv = tid >> 6;

  // ---- task decode ----
  const unsigned* tcnt = (const unsigned*)(ws + WS_STATS + 16);
  const int n_big = (int)tcnt[0], n_small = (int)tcnt[1];
  const int n_task = n_big + ((n_small + 1) >> 1);
  if ((int)(blockIdx.x * 4) >= n_task) return;   // block-uniform early exit
  const int slot = blockIdx.x * 4 + wv;
  const unsigned short* bigl = (const unsigned short*)(ws + WS_SWS);
  const unsigned short* smal = bigl + 16384;
  int p0 = -1, p1 = -1, big = 0;
  if (slot < n_big) { p0 = bigl[slot]; big = 1; }
  else if (slot < n_task) {
    int j = slot - n_big;
    p0 = smal[2 * j];
    if (2 * j + 1 < n_small) p1 = smal[2 * j + 1];
  }

  // ---- mask + row compaction (per wave) ----
  const int r = lane & 31, hh = lane >> 5;
  int pp = big ? (hh ? -1 : p0) : (hh ? p1 : p0);
  float a_val = 0.f;
  if (pp >= 0) a_val = adj[(((pp >> 5) * 32 + r) * 32) + (pp & 31)];
  const bool live = (a_val > 0.f) && (a_val < 1.f);
  unsigned long long bal = __ballot(live);
  unsigned hm = hh ? (unsigned)(bal >> 32) : (unsigned)bal;
  int pre = __popc(hm & ((1u << r) - 1u));
  int slot_in = big ? pre : (hh * 16 + pre);
  int cnt0, cnt1;
  if (big) { int ca = __popc((unsigned)bal); cnt0 = ca < 16 ? ca : 16; cnt1 = ca - cnt0; }
  else     { cnt0 = __popc((unsigned)bal); cnt1 = __popc((unsigned)(bal >> 32)); }
  unsigned* scr = (unsigned*)(smem + 10240 + wv * 128);   // slot -> src row
  if (live) scr[slot_in] = (unsigned)r;

  // ---- phase 0: compacted xj tile (stride 40) + WT0p via global_load_lds ----
  {
    const uint4* src = (const uint4*)xjb;
    char* tile = smem + wv * 2560;
    int j0 = lane >> 2, j1 = 16 + (lane >> 2), pt = lane & 3;
    int ca = cnt0 + cnt1;
    bool v0 = j0 < (big ? ca : cnt0);
    bool v1 = big ? (j1 < ca) : ((j1 - 16) < cnt1);
    int b0 = (p0 < 0 ? 0 : p0 >> 5);
    int b1 = (p1 < 0 ? 0 : p1 >> 5);
    int sb1 = big ? b0 : b1;
    unsigned sr0 = v0 ? scr[j0] : 0u;
    unsigned sr1 = v1 ? scr[j1] : 0u;
    uint4 z4 = {0u, 0u, 0u, 0u};
    uint4 q0 = v0 ? src[(b0 * 32 + (int)sr0) * 4 + pt] : z4;
    uint4 q1 = v1 ? src[(sb1 * 32 + (int)sr1) * 4 + pt] : z4;
    *(uint4*)(tile + j0 * 80 + pt * 16) = q0;
    *(uint4*)(tile + j1 * 80 + pt * 16) = q1;
    // e column patch (after tile writes; same-wave DS ordering)
    if (live) ((unsigned short*)(tile + slot_in * 80))[31] = f2bf(a_val);
  }
  // WT0p image: 10240 B contiguous
  {
    int off = tid * 16;
    gll16(WT0p + off, smem + SMP_W + off);
    gll16(WT0p + off + 4096, smem + SMP_W + off + 4096);
    if (tid < 128) gll16(WT0p + off + 8192, smem + SMP_W + off + 8192);
  }
  __syncthreads();

  f32x4 acc[2][8];

  // ---- layer 0: [32 pair rows] x [K=32] @ lin1 (bias in acc) ----
  bias_acc(acc, lin1_b, li);
  {
    const unsigned short* xt = (const unsigned short*)(smem + wv * 2560);
    bf16x8 a0 = lds_frag(xt + li * 40 + quad * 8);
    bf16x8 a1 = lds_frag(xt + (li + 16) * 40 + quad * 8);
#pragma unroll
    for (int tj = 0; tj < 8; ++tj) {
      bf16x8 bb = lds_frag(Wh + (tj * 16 + li) * 40 + quad * 8);
      acc[0][tj] = mfma16(a0, bb, acc[0][tj]);
      acc[1][tj] = mfma16(a1, bb, acc[1][tj]);
    }
  }
  __syncthreads();                       // drain A/B reads before overwrites
  stage18432(W1p, smem + SMP_W, tid);    // W1 half0 in flight during epilogue
  epilogue_store(acc, Xs, wv, li, quad);
  __syncthreads();

  // ---- hidden layer 1 (folded bias in acc) ----
  bias_acc(acc, g_bf, li);
  mfma_half(acc, Xs, Wh, 0, wv, li, quad);
  __syncthreads();
  stage18432(W1p + 18432, smem + SMP_W, tid);
  __syncthreads();
  mfma_half(acc, Xs, Wh, 64, wv, li, quad);
  __syncthreads();
  stage18432(W2p, smem + SMP_W, tid);
  epilogue_store(acc, Xs, wv, li, quad);
  __syncthreads();

  // ---- hidden layer 2 + masked aggregate ----
  bias_acc(acc, g_bf + 128, li);
  mfma_half(acc, Xs, Wh, 0, wv, li, quad);
  __syncthreads();
  stage18432(W2p + 18432, smem + SMP_W, tid);
  __syncthreads();
  mfma_half(acc, Xs, Wh, 64, wv, li, quad);

  epilogue_agg2(acc, lnh_g + 128, lnh_b + 128, big, cnt0, cnt1, p0, p1,
                agent_id, ws, li, quad);
}

// ---------------------------------------------------------------------------
// k_score: s[row] = relu(h@fc2a+b)@fc2b + b2 via MFMA, 128 rows/block,
// plus per-block softmax partials (max_b, sumexp_b) -> g_ms.  [NEW]
// ---------------------------------------------------------------------------
#define SC_TOTAL 70656
__global__ __launch_bounds__(256, 2)
void k_score(const char* __restrict__ ws,
             const float* __restrict__ fc2a_b, const float* __restrict__ fc2b_w,
             const float* __restrict__ fc2b_b) {
  __shared__ alignas(16) char smem[SC_TOTAL];
  __shared__ float scb[128];
  __shared__ float pr[4];
  unsigned short* Xs = (unsigned short*)smem;
  unsigned short* Ws = (unsigned short*)(smem + 34816);
  float* P = (float*)(smem + 69632);
  const int tid = threadIdx.x;
  const int row0 = blockIdx.x * 128;
  const uint4* hb4 = (const uint4*)(ws + WS_HB);
  const char* WT3p = ws + WS_WT3P;
  float* sws = (float*)((char*)ws + WS_SWS);

  for (int i = tid; i < 2048; i += 256) {      // hb rows -> padded Xs
    int row = i >> 4, ch = i & 15;
    uint4 v = hb4[(row0 + row) * 16 + ch];
    *(uint4*)(Xs + row * 136 + ch * 8) = v;
  }
  {                                            // WT3p image: 34816 B
    int off = tid * 16;
#pragma unroll
    for (int it = 0; it < 8; ++it) gll16(WT3p + off + it * 4096, smem + 34816 + off + it * 4096);
    if (tid < 128) gll16(WT3p + off + 32768, smem + 34816 + off + 32768);
  }
  if (tid < 128) { P[tid] = fc2a_b[tid]; P[128 + tid] = fc2b_w[tid]; }
  __syncthreads();

  const int lane = tid & 63, li = lane & 15, quad = lane >> 4, wv = tid >> 6;
  f32x4 acc[2][8];
#pragma unroll
  for (int ti = 0; ti < 2; ++ti)
#pragma unroll
    for (int tj = 0; tj < 8; ++tj)
#pragma unroll
      for (int q = 0; q < 4; ++q) acc[ti][tj][q] = 0.f;
#pragma unroll
  for (int s = 0; s < 4; ++s) {
    bf16x8 a0 = lds_frag(Xs + (32 * wv + li) * 136 + s * 32 + quad * 8);
    bf16x8 a1 = lds_frag(Xs + (32 * wv + 16 + li) * 136 + s * 32 + quad * 8);
#pragma unroll
    for (int tj = 0; tj < 8; ++tj) {
      bf16x8 bb = lds_frag(Ws + (tj * 16 + li) * 136 + s * 32 + quad * 8);
      acc[0][tj] = mfma16(a0, bb, acc[0][tj]);
      acc[1][tj] = mfma16(a1, bb, acc[1][tj]);
    }
  }
  float bs[8], w2[8];
#pragma unroll
  for (int tj = 0; tj < 8; ++tj) {
    bs[tj] = P[tj * 16 + li];
    w2[tj] = P[128 + tj * 16 + li];
  }
  float b2 = fc2b_b[0];
#pragma unroll
  for (int ti = 0; ti < 2; ++ti) {
#pragma unroll
    for (int rg = 0; rg < 4; ++rg) {
      float t = 0.f;
#pragma unroll
      for (int tj = 0; tj < 8; ++tj) {
        float x = acc[ti][tj][rg] + bs[tj];
        x = fmaxf(x, 0.f);
        t += x * w2[tj];
      }
#pragma unroll
      for (int m = 1; m < 16; m <<= 1) t += __shfl_xor(t, m);
      if (li == 0) {
        int rl = 32 * wv + ti * 16 + quad * 4 + rg;
        float sc = t + b2;
        sws[row0 + rl] = sc;
        scb[rl] = sc;
      }
    }
  }
  __syncthreads();
  // per-block softmax partials over the 128 scores
  if (tid < 128) {
    float m = scb[tid];
#pragma unroll
    for (int d = 1; d < 64; d <<= 1) m = fmaxf(m, __shfl_xor(m, d));
    if ((tid & 63) == 0) pr[tid >> 6] = m;
  }
  __syncthreads();
  float M_b = fmaxf(pr[0], pr[1]);
  if (tid < 128) {
    float e = __expf(scb[tid] - M_b);
#pragma unroll
    for (int d = 1; d < 64; d <<= 1) e += __shfl_xor(e, d);
    if ((tid & 63) == 0) pr[2 + (tid >> 6)] = e;
  }
  __syncthreads();
  if (tid == 0) { g_ms[blockIdx.x] = M_b; g_ms[128 + blockIdx.x] = pr[2] + pr[3]; }
}

// ---------------------------------------------------------------------------
// k_final: combine 128 softmax partials -> (M,S); then 512 agent rows.
// ---------------------------------------------------------------------------
__global__ __launch_bounds__(128)
void k_final(const char* __restrict__ ws, const int* __restrict__ agent_id,
             const float* __restrict__ fc3_w, const float* __restrict__ fc3_b,
             const float* __restrict__ ln3_g, const float* __restrict__ ln3_b,
             const float* __restrict__ fc4_w, const float* __restrict__ fc4_b,
             const float* __restrict__ ln4_g, const float* __restrict__ ln4_b,
             float* __restrict__ out) {
  const float* hsel  = (const float*)(ws + WS_HSEL);
  const float* sws   = (const float*)(ws + WS_SWS);
  __shared__ float xrow[128];
  __shared__ float red[8];
  __shared__ float pr[4];
  const int tid = threadIdx.x;
  const int b = blockIdx.x;

  // softmax stats from per-block partials (M = exact global max)
  float mv = g_ms[tid], sv = g_ms[128 + tid];
  {
    float m = mv;
#pragma unroll
    for (int d = 1; d < 64; d <<= 1) m = fmaxf(m, __shfl_xor(m, d));
    if ((tid & 63) == 0) pr[tid >> 6] = m;
  }
  xrow[tid] = hsel[b * 128 + tid];
  __syncthreads();
  float M = fmaxf(pr[0], pr[1]);
  {
    float e = __expf(mv - M) * sv;
#pragma unroll
    for (int d = 1; d < 64; d <<= 1) e += __shfl_xor(e, d);
    if ((tid & 63) == 0) pr[2 + (tid >> 6)] = e;
  }
  __syncthreads();
  float S = pr[2] + pr[3];

  float t = fc3_b[tid];
  for (int k = 0; k < 128; ++k) t += xrow[k] * fc3_w[k * 128 + tid];
  t = fmaxf(t, 0.f);
  float s1 = t, s2 = t * t;
#pragma unroll
  for (int m = 1; m < 64; m <<= 1) { s1 += __shfl_xor(s1, m); s2 += __shfl_xor(s2, m); }
  if ((tid & 63) == 0) { red[(tid >> 6) * 2] = s1; red[(tid >> 6) * 2 + 1] = s2; }
  __syncthreads();
  s1 = red[0] + red[2]; s2 = red[1] + red[3];
  float mean = s1 * 0.0078125f;
  float var  = s2 * 0.0078125f - mean * mean;
  float inv  = rsqrtf(var + 1e-5f);
  float v = (t - mean) * inv * ln3_g[tid] + ln3_b[tid];
  float alpha = __expf(sws[b * 32 + agent_id[b]] - M) / S;
  __syncthreads();
  xrow[tid] = alpha * v;
  __syncthreads();
  float x = fc4_b[tid];
  for (int k = 0; k < 128; ++k) x += xrow[k] * fc4_w[k * 128 + tid];
  x = fmaxf(x, 0.f);
  s1 = x; s2 = x * x;
#pragma unroll
  for (int m = 1; m < 64; m <<= 1) { s1 += __shfl_xor(s1, m); s2 += __shfl_xor(s2, m); }
  if ((tid & 63) == 0) { red[4 + (tid >> 6) * 2] = s1; red[5 + (tid >> 6) * 2] = s2; }
  __syncthreads();
  s1 = red[4] + red[6]; s2 = red[5] + red[7];
  mean = s1 * 0.0078125f;
  var  = s2 * 0.0078125f - mean * mean;
  inv  = rsqrtf(var + 1e-5f);
  out[b * 128 + tid] = (x - mean) * inv * ln4_g[tid] + ln4_b[tid];
}

// ---------------------------------------------------------------------------
extern "C" void kernel_launch(void* const* d_in, const int* in_sizes, int n_in,
                              void* d_out, int out_size, void* d_ws, size_t ws_size,
                              hipStream_t stream) {
  (void)in_sizes; (void)n_in; (void)out_size; (void)ws_size;
  const float* node_obs = (const float*)d_in[0];
  const float* adj      = (const float*)d_in[1];
  const int*   agent_id = (const int*)d_in[2];
  const float* ent_emb  = (const float*)d_in[3];
  const float* lin1_w   = (const float*)d_in[4];
  const float* lin1_b   = (const float*)d_in[5];
  const float* ln1_g    = (const float*)d_in[6];
  const float* ln1_beta = (const float*)d_in[7];
  const float* linh_w   = (const float*)d_in[8];
  const float* linh_b   = (const float*)d_in[9];
  const float* lnh_g    = (const float*)d_in[10];
  const float* lnh_b    = (const float*)d_in[11];
  // d_in[12] fc2a_w used in k_prep
  const float* fc2a_b   = (const float*)d_in[13];
  const float* fc2b_w   = (const float*)d_in[14];
  const float* fc2b_b   = (const float*)d_in[15];
  const float* fc3_w    = (const float*)d_in[16];
  const float* fc3_b    = (const float*)d_in[17];
  const float* ln3_g    = (const float*)d_in[18];
  const float* ln3_b    = (const float*)d_in[19];
  const float* fc4_w    = (const float*)d_in[20];
  const float* fc4_b    = (const float*)d_in[21];
  const float* ln4_g    = (const float*)d_in[22];
  const float* ln4_b    = (const float*)d_in[23];
  float* out = (float*)d_out;
  char* ws = (char*)d_ws;

  k_prep<<<(PREP_N5 + 255) / 256, 256, 0, stream>>>(node_obs, ent_emb, lin1_w, linh_w,
                                                    (const float*)d_in[12],
                                                    ln1_g, ln1_beta, lnh_g, lnh_b,
                                                    linh_b, ws);
  k_mask<<<64, 256, 0, stream>>>(adj, ws);
  k_pair<<<4096, 256, 0, stream>>>(adj, agent_id, lin1_b, lnh_g, lnh_b, ws);
  k_score<<<128, 256, 0, stream>>>(ws, fc2a_b, fc2b_w, fc2b_b);
  k_final<<<512, 128, 0, stream>>>(ws, agent_id,
                                   fc3_w, fc3_b, ln3_g, ln3_b,
                                   fc4_w, fc4_b, ln4_g, ln4_b, out);
}

// Round 8
// 179.912 us; speedup vs baseline: 1.0750x; 1.0174x over previous
//
#include <hip/hip_runtime.h>
#include <hip/hip_bf16.h>

// ---------------------------------------------------------------------------
// GNNBase: B=512, N=32, F=16, H=128, E=16, NE=3, L=2, D0=32
//   k_prep : MERGED prep+mask. Blocks [0,2281): xj table + pre-padded bf16
//            W^T images (LN affine folded, sigma-permuted) + folded biases.
//            Blocks [2281,2345): pair classification (big/small task lists,
//            block-aggregated compaction, 2 atomics/block). Counter zeroing
//            via hipMemsetAsync before launch (graph-capture-safe).
//   k_pair : wave-task = 2 MFMA row-tiles: one big pair (rows compacted) or
//            TWO packed small pairs. LN normalize-only in C-frag regs.
//                                                                [R3-proven]
//   k_score: scores via MFMA + per-block softmax partials -> g_ms [R7-proven]
//   k_final: combines 128 partials -> (M, S), then 512 agent rows [R7-proven]
//
// sigma column permutation: position p <-> orig channel
//   ch(p) = 32*(p>>5) + 16*(p&1) + ((p>>1)&15)
// ---------------------------------------------------------------------------

typedef __attribute__((ext_vector_type(8))) __bf16 bf16x8;
typedef __attribute__((ext_vector_type(4))) float  f32x4;
typedef __attribute__((ext_vector_type(2))) float  f32x2;

__device__ float g_bf[256];   // folded biases: [0:128)=layer1, [128:256)=layer2
__device__ float g_ms[256];   // softmax partials: [0:128)=max_b, [128:256)=sum_b

__device__ __forceinline__ unsigned short f2bf(float f) {
  union { float f; unsigned u; } v; v.f = f;
  unsigned u = v.u;
  u += 0x7FFFu + ((u >> 16) & 1u);   // RTNE
  return (unsigned short)(u >> 16);
}

__device__ __forceinline__ unsigned pk2bf(float a, float b) {
  union { __hip_bfloat162 h; unsigned u; } cv;
  cv.h = __float22bfloat162_rn(make_float2(a, b));   // .x -> low 16
  return cv.u;
}

__device__ __forceinline__ bf16x8 lds_frag(const unsigned short* p) {
  union { uint4 u; bf16x8 v; } x;
  x.u = *(const uint4*)p;            // ds_read_b128
  return x.v;
}

__device__ __forceinline__ f32x4 mfma16(bf16x8 a, bf16x8 b, f32x4 c) {
  return __builtin_amdgcn_mfma_f32_16x16x32_bf16(a, b, c, 0, 0, 0);
}

// 16-lane butterfly sum via DPP (returns full sum in all lanes of each row16)
__device__ __forceinline__ float dpp_add16(float x) {
  union { float f; int i; } a, t;
  a.f = x;
  t.i = __builtin_amdgcn_update_dpp(0, a.i, 0xB1,  0xF, 0xF, true); a.f += t.f; // quad_perm xor1
  t.i = __builtin_amdgcn_update_dpp(0, a.i, 0x4E,  0xF, 0xF, true); a.f += t.f; // quad_perm xor2
  t.i = __builtin_amdgcn_update_dpp(0, a.i, 0x141, 0xF, 0xF, true); a.f += t.f; // row_half_mirror
  t.i = __builtin_amdgcn_update_dpp(0, a.i, 0x140, 0xF, 0xF, true); a.f += t.f; // row_mirror
  return a.f;
}

// async global->LDS, 16 B per lane. LDS dest = wave-uniform base + lane*16.
__device__ __forceinline__ void gll16(const void* g, void* l) {
  __builtin_amdgcn_global_load_lds(
      (const __attribute__((address_space(1))) unsigned int*)(unsigned long long)g,
      (__attribute__((address_space(3))) unsigned int*)(unsigned int)(unsigned long long)l,
      16, 0, 0);
}

// copy a contiguous 18432-B pre-padded weight image into LDS (256 threads)
__device__ __forceinline__ void stage18432(const char* g, char* l, int tid) {
  int off = tid * 16;
  gll16(g + off,         l + off);
  gll16(g + off + 4096,  l + off + 4096);
  gll16(g + off + 8192,  l + off + 8192);
  gll16(g + off + 12288, l + off + 12288);
  if (tid < 128) gll16(g + off + 16384, l + off + 16384);
}

// ---------------------------------------------------------------------------
// workspace layout (bytes)
// ---------------------------------------------------------------------------
#define WS_HB    0           // bf16 h [16384][128] (sigma order)   4194304
#define WS_HSEL  4194304     // f32  h agent rows [512][128] (orig)  262144
#define WS_SWS   4456448     // f32 scores [16384] / task lists       65536
#define WS_STATS 4521984     // +16: task counters                      256
#define WS_XJB   4522240     // bf16 xj [16384][32]                 1048576
#define WS_WT0P  5570816     // bf16 lin1 W^T [128][40]               10240
#define WS_W1P   5581056     // bf16 folded linh0 W^T [2][128][72]    36864
#define WS_W2P   5617920     // bf16 folded linh1 W^T [2][128][72]    36864
#define WS_WT3P  5654784     // bf16 fc2a W^T [128][136] (sigma rows) 34816

// ---------------------------------------------------------------------------
// k_prep (merged prep + mask)
// ---------------------------------------------------------------------------
#define PREP_N0 524288                 // xjb elements
#define PREP_N1 (PREP_N0 + 5120)      // + WT0p [128][40]
#define PREP_N2 (PREP_N1 + 36864)     // + W1p/W2p [2l][2h][128][72]
#define PREP_N3 (PREP_N2 + 17408)     // + WT3p [128][136]
#define PREP_N4 (PREP_N3 + 256)      // + folded biases
#define PREP_BLKS 2281                // = PREP_N4 / 256 (exact)
#define MASK_BLKS 64
#define MERGED_BLKS (PREP_BLKS + MASK_BLKS)

__global__ void k_prep(const float* __restrict__ node_obs, const float* __restrict__ ent_emb,
                       const float* __restrict__ lin1_w, const float* __restrict__ linh_w,
                       const float* __restrict__ fc2a_w,
                       const float* __restrict__ ln1_g, const float* __restrict__ ln1_b,
                       const float* __restrict__ lnh_g, const float* __restrict__ lnh_b,
                       const float* __restrict__ linh_b,
                       const float* __restrict__ adj,
                       char* __restrict__ ws) {
  __shared__ unsigned sb[4], ss[4];
  __shared__ unsigned base_b, base_s;
  const int tid = threadIdx.x;

  if (blockIdx.x >= PREP_BLKS) {
    // ---- mask part: classify all 16384 (b,c) pairs ----
    const int lane = tid & 63, wv = tid >> 6;
    int p = (int)(blockIdx.x - PREP_BLKS) * 256 + tid;
    int b = p >> 5, c = p & 31;
    int cnt = 0;
#pragma unroll 8
    for (int r = 0; r < 32; ++r) {
      float a = adj[(b * 32 + r) * 32 + c];
      cnt += (a > 0.f && a < 1.f) ? 1 : 0;
    }
    const bool big = cnt > 16;
    unsigned long long bal = __ballot(big);
    if (lane == 0) {
      unsigned nb = (unsigned)__popcll(bal);
      sb[wv] = nb; ss[wv] = 64u - nb;
    }
    __syncthreads();
    if (tid == 0) {
      unsigned tb = 0, ts = 0;
#pragma unroll
      for (int i = 0; i < 4; ++i) {
        unsigned t = sb[i]; sb[i] = tb; tb += t;
        t = ss[i]; ss[i] = ts; ts += t;
      }
      unsigned* tcnt = (unsigned*)(ws + WS_STATS + 16);  // zeroed by memsetAsync
      base_b = atomicAdd(&tcnt[0], tb);
      base_s = atomicAdd(&tcnt[1], ts);
    }
    __syncthreads();
    unsigned long long mlow = (1ull << lane) - 1ull;
    unsigned short* bigl = (unsigned short*)(ws + WS_SWS);
    unsigned short* smal = bigl + 16384;
    if (big) {
      unsigned rk = base_b + sb[wv] + (unsigned)__popcll(bal & mlow);
      bigl[rk] = (unsigned short)p;
    } else {
      unsigned rk = base_s + ss[wv] + (unsigned)__popcll(~bal & mlow);
      smal[rk] = (unsigned short)p;
    }
    return;
  }

  // ---- prep part ----
  int idx = blockIdx.x * 256 + tid;
  unsigned short* xjb  = (unsigned short*)(ws + WS_XJB);
  unsigned short* WT0p = (unsigned short*)(ws + WS_WT0P);
  unsigned short* W1p  = (unsigned short*)(ws + WS_W1P);
  unsigned short* W2p  = (unsigned short*)(ws + WS_W2P);
  unsigned short* WT3p = (unsigned short*)(ws + WS_WT3P);
  if (idx < PREP_N0) {
    int row = idx >> 5, k = idx & 31;
    float val;
    if (k < 15) val = node_obs[row * 16 + k];
    else if (k < 31) {
      int ent = (int)node_obs[row * 16 + 15];
      val = ent_emb[ent * 16 + (k - 15)];
    } else val = 0.f;   // e slot, patched per-wave in k_pair
    xjb[idx] = f2bf(val);
  } else if (idx < PREP_N1) {
    int r = idx - PREP_N0;
    int n = r / 40, kk = r - n * 40;
    WT0p[n * 40 + kk] = (kk < 32) ? f2bf(lin1_w[kk * 128 + n]) : (unsigned short)0;
  } else if (idx < PREP_N2) {
    int r = idx - PREP_N1;
    int l = r / 18432; r -= l * 18432;
    int h = r / 9216;  r -= h * 9216;
    int n = r / 72;    int kk = r - n * 72;
    unsigned short v = 0;
    if (kk < 64) {
      int p  = h * 64 + kk;                                    // sigma position
      int ok = 32 * (p >> 5) + 16 * (p & 1) + ((p >> 1) & 15); // orig channel
      float g = l ? lnh_g[ok] : ln1_g[ok];                     // fold prev LN gain
      v = f2bf(g * linh_w[l * 16384 + ok * 128 + n]);
    }
    (l ? W2p : W1p)[h * 9216 + n * 72 + kk] = v;
  } else if (idx < PREP_N3) {
    int r = idx - PREP_N2;
    int n = r / 136, kk = r - n * 136;
    unsigned short v = 0;
    if (kk < 128) {
      int ok = 32 * (kk >> 5) + 16 * (kk & 1) + ((kk >> 1) & 15);
      v = f2bf(fc2a_w[ok * 128 + n]);
    }
    WT3p[n * 136 + kk] = v;
  } else if (idx < PREP_N4) {
    // folded biases: b'[n] = linh_b[l][n] + beta_prev @ W[l][:,n]
    int r = idx - PREP_N3;
    int which = r >> 7, n = r & 127;
    const float* be = which ? lnh_b : ln1_b;   // beta of the preceding LN
    const float* w  = linh_w + which * 16384 + n;
    float a = linh_b[which * 128 + n];
#pragma unroll 8
    for (int k = 0; k < 128; ++k) a += be[k] * w[k * 128];
    g_bf[which * 128 + n] = a;
  }
}

// ---------------------------------------------------------------------------
// epilogues. C-frag (16x16x32): col = tj*16+(lane&15), row = ti*16+quad*4+reg.
// ---------------------------------------------------------------------------
__device__ __forceinline__ void bias_acc(f32x4 (&acc)[2][8],
                                         const float* __restrict__ gb, int li) {
#pragma unroll
  for (int tj = 0; tj < 8; ++tj) {
    float b = gb[tj * 16 + li];
#pragma unroll
    for (int ti = 0; ti < 2; ++ti)
#pragma unroll
      for (int q = 0; q < 4; ++q) acc[ti][tj][q] = b;
  }
}

__device__ __forceinline__ void epilogue_store(f32x4 (&acc)[2][8],
    unsigned short* Xs, int wv, int li, int quad) {
  const f32x2 z2 = {0.f, 0.f};
#pragma unroll
  for (int ti = 0; ti < 2; ++ti) {
#pragma unroll
    for (int rp = 0; rp < 2; ++rp) {          // row pair (2*rp, 2*rp+1)
      f32x2 vv[8], s1 = {0.f, 0.f}, s2 = {0.f, 0.f};
#pragma unroll
      for (int tj = 0; tj < 8; ++tj) {
        f32x2 x = { acc[ti][tj][2 * rp], acc[ti][tj][2 * rp + 1] };
        x = __builtin_elementwise_max(x, z2);   // relu (v_pk_max_f32)
        vv[tj] = x; s1 += x; s2 += x * x;
      }
      f32x2 S1 = { dpp_add16(s1.x), dpp_add16(s1.y) };
      f32x2 S2 = { dpp_add16(s2.x), dpp_add16(s2.y) };
      f32x2 mean = S1 * 0.0078125f;
      f32x2 var  = S2 * 0.0078125f - mean * mean;
      f32x2 inv  = { rsqrtf(var.x + 1e-5f), rsqrtf(var.y + 1e-5f) };
      f32x2 c0   = -mean * inv;
      int r0 = 32 * wv + ti * 16 + quad * 4 + 2 * rp;
      unsigned* d0 = (unsigned*)(Xs + r0 * 136);
      unsigned* d1 = (unsigned*)(Xs + (r0 + 1) * 136);
#pragma unroll
      for (int g4 = 0; g4 < 4; ++g4) {
        f32x2 oa = vv[2 * g4]     * inv + c0;   // sigma-even col
        f32x2 ob = vv[2 * g4 + 1] * inv + c0;   // sigma-odd col
        d0[g4 * 16 + li] = pk2bf(oa.x, ob.x);   // ds_write_b32, 2-way = free
        d1[g4 * 16 + li] = pk2bf(oa.y, ob.y);
      }
    }
  }
}

// quad-reduce T/Q and write one h row (sigma-order bf16) + optional hsel (f32).
__device__ __forceinline__ void agg_reduce_write(float (&T)[8], float Q, float NM,
    const float* __restrict__ gg, const float* __restrict__ gbe,
    int pair, const int* __restrict__ agent_id, char* __restrict__ ws,
    int li, int quad) {
#pragma unroll
  for (int tj = 0; tj < 8; ++tj) {
    T[tj] += __shfl_xor(T[tj], 16);
    T[tj] += __shfl_xor(T[tj], 32);
  }
  Q += __shfl_xor(Q, 16); Q += __shfl_xor(Q, 32);
  if (quad != 0 || pair < 0) return;
  float cs[8];
#pragma unroll
  for (int tj = 0; tj < 8; ++tj) {
    int col = tj * 16 + li;
    cs[tj] = gg[col] * (T[tj] - Q) + NM * gbe[col];
  }
  unsigned* hb32 = (unsigned*)((unsigned short*)(ws + WS_HB) + pair * 128);
#pragma unroll
  for (int g4 = 0; g4 < 4; ++g4)
    hb32[g4 * 16 + li] = pk2bf(cs[2 * g4], cs[2 * g4 + 1]);
  int b = pair >> 5;
  if ((pair & 31) == agent_id[b]) {
    float* hs = (float*)(ws + WS_HSEL) + b * 128;
#pragma unroll
    for (int tj = 0; tj < 8; ++tj) hs[tj * 16 + li] = cs[tj];  // orig order
  }
}

// final layer: normalize then masked sum. Compacted rows are live-contiguous:
// mask = (row < cnt), NM = cnt (scalar). Big pair: tiles sum to one dest;
// small pairs: one dest per tile.
__device__ __forceinline__ void epilogue_agg2(f32x4 (&acc)[2][8],
    const float* __restrict__ gg, const float* __restrict__ gbe,
    int big, int cnt0, int cnt1, int p0, int p1,
    const int* __restrict__ agent_id, char* __restrict__ ws,
    int li, int quad) {
  const f32x2 z2 = {0.f, 0.f};
  float T0[8], T1[8], Q0 = 0.f, Q1 = 0.f;
#pragma unroll
  for (int ti = 0; ti < 2; ++ti) {
    f32x2 Tp[8];
#pragma unroll
    for (int tj = 0; tj < 8; ++tj) Tp[tj] = z2;
    f32x2 Qp = z2;
    float lim   = big ? (float)(cnt0 + cnt1) : (float)(ti ? cnt1 : cnt0);
    float rbase = (float)((big ? ti * 16 : 0) + quad * 4);
#pragma unroll
    for (int rp = 0; rp < 2; ++rp) {
      f32x2 vv[8], s1 = z2, s2 = z2;
#pragma unroll
      for (int tj = 0; tj < 8; ++tj) {
        f32x2 x = { acc[ti][tj][2 * rp], acc[ti][tj][2 * rp + 1] };
        x = __builtin_elementwise_max(x, z2);
        vv[tj] = x; s1 += x; s2 += x * x;
      }
      f32x2 S1 = { dpp_add16(s1.x), dpp_add16(s1.y) };
      f32x2 S2 = { dpp_add16(s2.x), dpp_add16(s2.y) };
      f32x2 mean = S1 * 0.0078125f;
      f32x2 var  = S2 * 0.0078125f - mean * mean;
      f32x2 inv  = { rsqrtf(var.x + 1e-5f), rsqrtf(var.y + 1e-5f) };
      float r0f = rbase + (float)(2 * rp);
      f32x2 mk = { (r0f < lim) ? 1.f : 0.f, (r0f + 1.f < lim) ? 1.f : 0.f };
      f32x2 u = mk * inv;
      Qp += u * mean;
#pragma unroll
      for (int tj = 0; tj < 8; ++tj) Tp[tj] += u * vv[tj];
    }
    if (ti == 0) {
#pragma unroll
      for (int tj = 0; tj < 8; ++tj) T0[tj] = Tp[tj].x + Tp[tj].y;
      Q0 = Qp.x + Qp.y;
    } else {
#pragma unroll
      for (int tj = 0; tj < 8; ++tj) T1[tj] = Tp[tj].x + Tp[tj].y;
      Q1 = Qp.x + Qp.y;
    }
  }
  if (big) {
#pragma unroll
    for (int tj = 0; tj < 8; ++tj) T0[tj] += T1[tj];
    Q0 += Q1;
    agg_reduce_write(T0, Q0, (float)(cnt0 + cnt1), gg, gbe, p0, agent_id, ws, li, quad);
  } else {
    agg_reduce_write(T0, Q0, (float)cnt0, gg, gbe, p0, agent_id, ws, li, quad);
    agg_reduce_write(T1, Q1, (float)cnt1, gg, gbe, p1, agent_id, ws, li, quad);
  }
}

// ---------------------------------------------------------------------------
// k_pair. LDS: Xs [128][136] bf16 (first 10240 B overlaid by 4 per-wave
// 32x40 xj tiles during layer 0; +128 B/wave compaction scratch above) +
// Wh [128][72] bf16 half-K weight buffer. 53248 B -> 3 blocks/CU. [R3-proven]
// ---------------------------------------------------------------------------
#define SMP_W 34816
#define SMP_TOTAL 53248

__device__ __forceinline__ void mfma_half(f32x4 (&acc)[2][8],
    const unsigned short* Xs, const unsigned short* Wh,
    int xoff, int wv, int li, int quad) {
#pragma unroll
  for (int s = 0; s < 2; ++s) {
    bf16x8 a0 = lds_frag(Xs + (32 * wv + li) * 136 + xoff + s * 32 + quad * 8);
    bf16x8 a1 = lds_frag(Xs + (32 * wv + 16 + li) * 136 + xoff + s * 32 + quad * 8);
#pragma unroll
    for (int tj = 0; tj < 8; ++tj) {
      bf16x8 bb = lds_frag(Wh + (tj * 16 + li) * 72 + s * 32 + quad * 8);
      acc[0][tj] = mfma16(a0, bb, acc[0][tj]);
      acc[1][tj] = mfma16(a1, bb, acc[1][tj]);
    }
  }
}

__global__ __launch_bounds__(256, 3)
void k_pair(const float* __restrict__ adj, const int* __restrict__ agent_id,
            const float* __restrict__ lin1_b,
            const float* __restrict__ lnh_g, const float* __restrict__ lnh_b,
            char* __restrict__ ws) {
  __shared__ alignas(16) char smem[SMP_TOTAL];
  unsigned short* Xs = (unsigned short*)smem;
  unsigned short* Wh = (unsigned short*)(smem + SMP_W);

  const unsigned short* xjb = (const unsigned short*)(ws + WS_XJB);
  const char* WT0p = ws + WS_WT0P;
  const char* W1p  = ws + WS_W1P;
  const char* W2p  = ws + WS_W2P;

  const int tid  = threadIdx.x;
  const int lane = tid & 63, li = lane & 15, quad = lane >> 4, wv = tid >> 6;

  // ---- task decode ----
  const unsigned* tcnt = (const unsigned*)(ws + WS_STATS + 16);
  const int n_big = (int)tcnt[0], n_small = (int)tcnt[1];
  const int n_task = n_big + ((n_small + 1) >> 1);
  if ((int)(blockIdx.x * 4) >= n_task) return;   // block-uniform early exit
  const int slot = blockIdx.x * 4 + wv;
  const unsigned short* bigl = (const unsigned short*)(ws + WS_SWS);
  const unsigned short* smal = bigl + 16384;
  int p0 = -1, p1 = -1, big = 0;
  if (slot < n_big) { p0 = bigl[slot]; big = 1; }
  else if (slot < n_task) {
    int j = slot - n_big;
    p0 = smal[2 * j];
    if (2 * j + 1 < n_small) p1 = smal[2 * j + 1];
  }

  // ---- mask + row compaction (per wave) ----
  const int r = lane & 31, hh = lane >> 5;
  int pp = big ? (hh ? -1 : p0) : (hh ? p1 : p0);
  float a_val = 0.f;
  if (pp >= 0) a_val = adj[(((pp >> 5) * 32 + r) * 32) + (pp & 31)];
  const bool live = (a_val > 0.f) && (a_val < 1.f);
  unsigned long long bal = __ballot(live);
  unsigned hm = hh ? (unsigned)(bal >> 32) : (unsigned)bal;
  int pre = __popc(hm & ((1u << r) - 1u));
  int slot_in = big ? pre : (hh * 16 + pre);
  int cnt0, cnt1;
  if (big) { int ca = __popc((unsigned)bal); cnt0 = ca < 16 ? ca : 16; cnt1 = ca - cnt0; }
  else     { cnt0 = __popc((unsigned)bal); cnt1 = __popc((unsigned)(bal >> 32)); }
  unsigned* scr = (unsigned*)(smem + 10240 + wv * 128);   // slot -> src row
  if (live) scr[slot_in] = (unsigned)r;

  // ---- phase 0: compacted xj tile (stride 40) + WT0p via global_load_lds ----
  {
    const uint4* src = (const uint4*)xjb;
    char* tile = smem + wv * 2560;
    int j0 = lane >> 2, j1 = 16 + (lane >> 2), pt = lane & 3;
    int ca = cnt0 + cnt1;
    bool v0 = j0 < (big ? ca : cnt0);
    bool v1 = big ? (j1 < ca) : ((j1 - 16) < cnt1);
    int b0 = (p0 < 0 ? 0 : p0 >> 5);
    int b1 = (p1 < 0 ? 0 : p1 >> 5);
    int sb1 = big ? b0 : b1;
    unsigned sr0 = v0 ? scr[j0] : 0u;
    unsigned sr1 = v1 ? scr[j1] : 0u;
    uint4 z4 = {0u, 0u, 0u, 0u};
    uint4 q0 = v0 ? src[(b0 * 32 + (int)sr0) * 4 + pt] : z4;
    uint4 q1 = v1 ? src[(sb1 * 32 + (int)sr1) * 4 + pt] : z4;
    *(uint4*)(tile + j0 * 80 + pt * 16) = q0;
    *(uint4*)(tile + j1 * 80 + pt * 16) = q1;
    // e column patch (after tile writes; same-wave DS ordering)
    if (live) ((unsigned short*)(tile + slot_in * 80))[31] = f2bf(a_val);
  }
  // WT0p image: 10240 B contiguous
  {
    int off = tid * 16;
    gll16(WT0p + off, smem + SMP_W + off);
    gll16(WT0p + off + 4096, smem + SMP_W + off + 4096);
    if (tid < 128) gll16(WT0p + off + 8192, smem + SMP_W + off + 8192);
  }
  __syncthreads();

  f32x4 acc[2][8];

  // ---- layer 0: [32 pair rows] x [K=32] @ lin1 (bias in acc) ----
  bias_acc(acc, lin1_b, li);
  {
    const unsigned short* xt = (const unsigned short*)(smem + wv * 2560);
    bf16x8 a0 = lds_frag(xt + li * 40 + quad * 8);
    bf16x8 a1 = lds_frag(xt + (li + 16) * 40 + quad * 8);
#pragma unroll
    for (int tj = 0; tj < 8; ++tj) {
      bf16x8 bb = lds_frag(Wh + (tj * 16 + li) * 40 + quad * 8);
      acc[0][tj] = mfma16(a0, bb, acc[0][tj]);
      acc[1][tj] = mfma16(a1, bb, acc[1][tj]);
    }
  }
  __syncthreads();                       // drain A/B reads before overwrites
  stage18432(W1p, smem + SMP_W, tid);    // W1 half0 in flight during epilogue
  epilogue_store(acc, Xs, wv, li, quad);
  __syncthreads();

  // ---- hidden layer 1 (folded bias in acc) ----
  bias_acc(acc, g_bf, li);
  mfma_half(acc, Xs, Wh, 0, wv, li, quad);
  __syncthreads();
  stage18432(W1p + 18432, smem + SMP_W, tid);
  __syncthreads();
  mfma_half(acc, Xs, Wh, 64, wv, li, quad);
  __syncthreads();
  stage18432(W2p, smem + SMP_W, tid);
  epilogue_store(acc, Xs, wv, li, quad);
  __syncthreads();

  // ---- hidden layer 2 + masked aggregate ----
  bias_acc(acc, g_bf + 128, li);
  mfma_half(acc, Xs, Wh, 0, wv, li, quad);
  __syncthreads();
  stage18432(W2p + 18432, smem + SMP_W, tid);
  __syncthreads();
  mfma_half(acc, Xs, Wh, 64, wv, li, quad);

  epilogue_agg2(acc, lnh_g + 128, lnh_b + 128, big, cnt0, cnt1, p0, p1,
                agent_id, ws, li, quad);
}

// ---------------------------------------------------------------------------
// k_score: s[row] = relu(h@fc2a+b)@fc2b + b2 via MFMA, 128 rows/block,
// plus per-block softmax partials (max_b, sumexp_b) -> g_ms.  [R7-proven]
// ---------------------------------------------------------------------------
#define SC_TOTAL 70656
__global__ __launch_bounds__(256, 2)
void k_score(const char* __restrict__ ws,
             const float* __restrict__ fc2a_b, const float* __restrict__ fc2b_w,
             const float* __restrict__ fc2b_b) {
  __shared__ alignas(16) char smem[SC_TOTAL];
  __shared__ float scb[128];
  __shared__ float pr[4];
  unsigned short* Xs = (unsigned short*)smem;
  unsigned short* Ws = (unsigned short*)(smem + 34816);
  float* P = (float*)(smem + 69632);
  const int tid = threadIdx.x;
  const int row0 = blockIdx.x * 128;
  const uint4* hb4 = (const uint4*)(ws + WS_HB);
  const char* WT3p = ws + WS_WT3P;
  float* sws = (float*)((char*)ws + WS_SWS);

  for (int i = tid; i < 2048; i += 256) {      // hb rows -> padded Xs
    int row = i >> 4, ch = i & 15;
    uint4 v = hb4[(row0 + row) * 16 + ch];
    *(uint4*)(Xs + row * 136 + ch * 8) = v;
  }
  {                                            // WT3p image: 34816 B
    int off = tid * 16;
#pragma unroll
    for (int it = 0; it < 8; ++it) gll16(WT3p + off + it * 4096, smem + 34816 + off + it * 4096);
    if (tid < 128) gll16(WT3p + off + 32768, smem + 34816 + off + 32768);
  }
  if (tid < 128) { P[tid] = fc2a_b[tid]; P[128 + tid] = fc2b_w[tid]; }
  __syncthreads();

  const int lane = tid & 63, li = lane & 15, quad = lane >> 4, wv = tid >> 6;
  f32x4 acc[2][8];
#pragma unroll
  for (int ti = 0; ti < 2; ++ti)
#pragma unroll
    for (int tj = 0; tj < 8; ++tj)
#pragma unroll
      for (int q = 0; q < 4; ++q) acc[ti][tj][q] = 0.f;
#pragma unroll
  for (int s = 0; s < 4; ++s) {
    bf16x8 a0 = lds_frag(Xs + (32 * wv + li) * 136 + s * 32 + quad * 8);
    bf16x8 a1 = lds_frag(Xs + (32 * wv + 16 + li) * 136 + s * 32 + quad * 8);
#pragma unroll
    for (int tj = 0; tj < 8; ++tj) {
      bf16x8 bb = lds_frag(Ws + (tj * 16 + li) * 136 + s * 32 + quad * 8);
      acc[0][tj] = mfma16(a0, bb, acc[0][tj]);
      acc[1][tj] = mfma16(a1, bb, acc[1][tj]);
    }
  }
  float bs[8], w2[8];
#pragma unroll
  for (int tj = 0; tj < 8; ++tj) {
    bs[tj] = P[tj * 16 + li];
    w2[tj] = P[128 + tj * 16 + li];
  }
  float b2 = fc2b_b[0];
#pragma unroll
  for (int ti = 0; ti < 2; ++ti) {
#pragma unroll
    for (int rg = 0; rg < 4; ++rg) {
      float t = 0.f;
#pragma unroll
      for (int tj = 0; tj < 8; ++tj) {
        float x = acc[ti][tj][rg] + bs[tj];
        x = fmaxf(x, 0.f);
        t += x * w2[tj];
      }
#pragma unroll
      for (int m = 1; m < 16; m <<= 1) t += __shfl_xor(t, m);
      if (li == 0) {
        int rl = 32 * wv + ti * 16 + quad * 4 + rg;
        float sc = t + b2;
        sws[row0 + rl] = sc;
        scb[rl] = sc;
      }
    }
  }
  __syncthreads();
  // per-block softmax partials over the 128 scores
  if (tid < 128) {
    float m = scb[tid];
#pragma unroll
    for (int d = 1; d < 64; d <<= 1) m = fmaxf(m, __shfl_xor(m, d));
    if ((tid & 63) == 0) pr[tid >> 6] = m;
  }
  __syncthreads();
  float M_b = fmaxf(pr[0], pr[1]);
  if (tid < 128) {
    float e = __expf(scb[tid] - M_b);
#pragma unroll
    for (int d = 1; d < 64; d <<= 1) e += __shfl_xor(e, d);
    if ((tid & 63) == 0) pr[2 + (tid >> 6)] = e;
  }
  __syncthreads();
  if (tid == 0) { g_ms[blockIdx.x] = M_b; g_ms[128 + blockIdx.x] = pr[2] + pr[3]; }
}

// ---------------------------------------------------------------------------
// k_final: combine 128 softmax partials -> (M,S); then 512 agent rows.
// ---------------------------------------------------------------------------
__global__ __launch_bounds__(128)
void k_final(const char* __restrict__ ws, const int* __restrict__ agent_id,
             const float* __restrict__ fc3_w, const float* __restrict__ fc3_b,
             const float* __restrict__ ln3_g, const float* __restrict__ ln3_b,
             const float* __restrict__ fc4_w, const float* __restrict__ fc4_b,
             const float* __restrict__ ln4_g, const float* __restrict__ ln4_b,
             float* __restrict__ out) {
  const float* hsel  = (const float*)(ws + WS_HSEL);
  const float* sws   = (const float*)(ws + WS_SWS);
  __shared__ float xrow[128];
  __shared__ float red[8];
  __shared__ float pr[4];
  const int tid = threadIdx.x;
  const int b = blockIdx.x;

  // softmax stats from per-block partials (M = exact global max)
  float mv = g_ms[tid], sv = g_ms[128 + tid];
  {
    float m = mv;
#pragma unroll
    for (int d = 1; d < 64; d <<= 1) m = fmaxf(m, __shfl_xor(m, d));
    if ((tid & 63) == 0) pr[tid >> 6] = m;
  }
  xrow[tid] = hsel[b * 128 + tid];
  __syncthreads();
  float M = fmaxf(pr[0], pr[1]);
  {
    float e = __expf(mv - M) * sv;
#pragma unroll
    for (int d = 1; d < 64; d <<= 1) e += __shfl_xor(e, d);
    if ((tid & 63) == 0) pr[2 + (tid >> 6)] = e;
  }
  __syncthreads();
  float S = pr[2] + pr[3];

  float t = fc3_b[tid];
  for (int k = 0; k < 128; ++k) t += xrow[k] * fc3_w[k * 128 + tid];
  t = fmaxf(t, 0.f);
  float s1 = t, s2 = t * t;
#pragma unroll
  for (int m = 1; m < 64; m <<= 1) { s1 += __shfl_xor(s1, m); s2 += __shfl_xor(s2, m); }
  if ((tid & 63) == 0) { red[(tid >> 6) * 2] = s1; red[(tid >> 6) * 2 + 1] = s2; }
  __syncthreads();
  s1 = red[0] + red[2]; s2 = red[1] + red[3];
  float mean = s1 * 0.0078125f;
  float var  = s2 * 0.0078125f - mean * mean;
  float inv  = rsqrtf(var + 1e-5f);
  float v = (t - mean) * inv * ln3_g[tid] + ln3_b[tid];
  float alpha = __expf(sws[b * 32 + agent_id[b]] - M) / S;
  __syncthreads();
  xrow[tid] = alpha * v;
  __syncthreads();
  float x = fc4_b[tid];
  for (int k = 0; k < 128; ++k) x += xrow[k] * fc4_w[k * 128 + tid];
  x = fmaxf(x, 0.f);
  s1 = x; s2 = x * x;
#pragma unroll
  for (int m = 1; m < 64; m <<= 1) { s1 += __shfl_xor(s1, m); s2 += __shfl_xor(s2, m); }
  if ((tid & 63) == 0) { red[4 + (tid >> 6) * 2] = s1; red[5 + (tid >> 6) * 2] = s2; }
  __syncthreads();
  s1 = red[4] + red[6]; s2 = red[5] + red[7];
  mean = s1 * 0.0078125f;
  var  = s2 * 0.0078125f - mean * mean;
  inv  = rsqrtf(var + 1e-5f);
  out[b * 128 + tid] = (x - mean) * inv * ln4_g[tid] + ln4_b[tid];
}

// ---------------------------------------------------------------------------
extern "C" void kernel_launch(void* const* d_in, const int* in_sizes, int n_in,
                              void* d_out, int out_size, void* d_ws, size_t ws_size,
                              hipStream_t stream) {
  (void)in_sizes; (void)n_in; (void)out_size; (void)ws_size;
  const float* node_obs = (const float*)d_in[0];
  const float* adj      = (const float*)d_in[1];
  const int*   agent_id = (const int*)d_in[2];
  const float* ent_emb  = (const float*)d_in[3];
  const float* lin1_w   = (const float*)d_in[4];
  const float* lin1_b   = (const float*)d_in[5];
  const float* ln1_g    = (const float*)d_in[6];
  const float* ln1_beta = (const float*)d_in[7];
  const float* linh_w   = (const float*)d_in[8];
  const float* linh_b   = (const float*)d_in[9];
  const float* lnh_g    = (const float*)d_in[10];
  const float* lnh_b    = (const float*)d_in[11];
  // d_in[12] fc2a_w used in k_prep
  const float* fc2a_b   = (const float*)d_in[13];
  const float* fc2b_w   = (const float*)d_in[14];
  const float* fc2b_b   = (const float*)d_in[15];
  const float* fc3_w    = (const float*)d_in[16];
  const float* fc3_b    = (const float*)d_in[17];
  const float* ln3_g    = (const float*)d_in[18];
  const float* ln3_b    = (const float*)d_in[19];
  const float* fc4_w    = (const float*)d_in[20];
  const float* fc4_b    = (const float*)d_in[21];
  const float* ln4_g    = (const float*)d_in[22];
  const float* ln4_b    = (const float*)d_in[23];
  float* out = (float*)d_out;
  char* ws = (char*)d_ws;

  // zero the two task counters (graph-capture-safe stream op)
  hipMemsetAsync(ws + WS_STATS + 16, 0, 8, stream);
  k_prep<<<MERGED_BLKS, 256, 0, stream>>>(node_obs, ent_emb, lin1_w, linh_w,
                                          (const float*)d_in[12],
                                          ln1_g, ln1_beta, lnh_g, lnh_b,
                                          linh_b, adj, ws);
  k_pair<<<4096, 256, 0, stream>>>(adj, agent_id, lin1_b, lnh_g, lnh_b, ws);
  k_score<<<128, 256, 0, stream>>>(ws, fc2a_b, fc2b_w, fc2b_b);
  k_final<<<512, 128, 0, stream>>>(ws, agent_id,
                                   fc3_w, fc3_b, ln3_g, ln3_b,
                                   fc4_w, fc4_b, ln4_g, ln4_b, out);
}